// Round 1
// baseline (1165.139 us; speedup 1.0000x reference)
//
#include <hip/hip_runtime.h>
#include <cmath>

#define D_MODEL 1024
#define NH 16
#define HD 64
#define BSZ 2
#define SEQ 2048
#define MTOT (BSZ * SEQ)   // 4096

// ---------------------------------------------------------------------------
// Tiled fp32 GEMM: C[M][N] = A[M][K] * B[K][N], 128x128 tile, 8x8 per thread.
// MODE 0: QKV epilogue -> scatter into Q/K/V [B][H][T][64], Q scaled by 0.125
// MODE 1: plain epilogue -> row-major out
// ---------------------------------------------------------------------------
template <int MODE>
__global__ __launch_bounds__(256)
void gemm128(const float* __restrict__ A, const float* __restrict__ B,
             float* __restrict__ outp,
             float* __restrict__ Qw, float* __restrict__ Kw, float* __restrict__ Vw,
             int M, int N, int Kdim)
{
    __shared__ float As[16][132];  // [k][m] (A transposed), padded
    __shared__ float Bs[16][132];  // [k][n], padded

    const int t  = threadIdx.x;
    const int m0 = blockIdx.y * 128;
    const int n0 = blockIdx.x * 128;
    const int tr = t >> 4;   // 0..15
    const int tc = t & 15;   // 0..15

    float acc[8][8];
#pragma unroll
    for (int i = 0; i < 8; ++i)
#pragma unroll
        for (int j = 0; j < 8; ++j) acc[i][j] = 0.0f;

    for (int k0 = 0; k0 < Kdim; k0 += 16) {
        // Stage A tile (128x16) transposed, and B tile (16x128).
#pragma unroll
        for (int s = 0; s < 2; ++s) {
            const int ar = (t >> 2) + 64 * s;        // 0..127
            const int ac = (t & 3) * 4;              // 0,4,8,12
            float4 av = *(const float4*)(A + (size_t)(m0 + ar) * Kdim + k0 + ac);
            As[ac + 0][ar] = av.x;
            As[ac + 1][ar] = av.y;
            As[ac + 2][ar] = av.z;
            As[ac + 3][ar] = av.w;

            const int br = (t >> 5) + 8 * s;         // 0..15
            const int bc = (t & 31) * 4;             // 0..124
            float4 bv = *(const float4*)(B + (size_t)(k0 + br) * N + n0 + bc);
            *(float4*)(&Bs[br][bc]) = bv;
        }
        __syncthreads();

#pragma unroll
        for (int k = 0; k < 16; ++k) {
            float a[8], b[8];
            *(float4*)(a)     = *(const float4*)(&As[k][tr * 8]);
            *(float4*)(a + 4) = *(const float4*)(&As[k][tr * 8 + 4]);
            *(float4*)(b)     = *(const float4*)(&Bs[k][tc * 8]);
            *(float4*)(b + 4) = *(const float4*)(&Bs[k][tc * 8 + 4]);
#pragma unroll
            for (int i = 0; i < 8; ++i)
#pragma unroll
                for (int j = 0; j < 8; ++j)
                    acc[i][j] = fmaf(a[i], b[j], acc[i][j]);
        }
        __syncthreads();
    }

    if (MODE == 1) {
#pragma unroll
        for (int i = 0; i < 8; ++i) {
            const int m = m0 + tr * 8 + i;
            float* dst = outp + (size_t)m * N + n0 + tc * 8;
            *(float4*)(dst)     = make_float4(acc[i][0], acc[i][1], acc[i][2], acc[i][3]);
            *(float4*)(dst + 4) = make_float4(acc[i][4], acc[i][5], acc[i][6], acc[i][7]);
        }
    } else {
        // n = n0 + tc*8 + j ; which matrix is uniform per block (1024 % 128 == 0)
        const int which = n0 >> 10;
        const int h     = ((n0 & 1023) >> 6) + (tc >> 3);
        const int d0    = (tc & 7) * 8;
        float* dst = (which == 0) ? Qw : (which == 1) ? Kw : Vw;
        const float sc = (which == 0) ? 0.125f : 1.0f;  // 1/sqrt(64) on Q
#pragma unroll
        for (int i = 0; i < 8; ++i) {
            const int m  = m0 + tr * 8 + i;
            const int b  = m >> 11;          // / SEQ
            const int tt = m & (SEQ - 1);
            float* p = dst + (((size_t)(b * NH + h) * SEQ) + tt) * HD + d0;
            *(float4*)(p)     = make_float4(acc[i][0] * sc, acc[i][1] * sc,
                                            acc[i][2] * sc, acc[i][3] * sc);
            *(float4*)(p + 4) = make_float4(acc[i][4] * sc, acc[i][5] * sc,
                                            acc[i][6] * sc, acc[i][7] * sc);
        }
    }
}

// ---------------------------------------------------------------------------
// Flash-style attention, fp32 VALU. One block = (bh, 32-query tile).
// Thread map: r = t/8 (query row in tile), u = t%8 (sub-lane).
//   S compute: thread owns score cols c = u + 8j  (stride-1 across u -> LDS
//              ds_read_b128 start banks distinct, conflict-free)
//   PV/output: thread owns out dims d = u*8 + jj (2-way LDS aliasing = free)
// ---------------------------------------------------------------------------
#define QT 32
#define KT 64

__global__ __launch_bounds__(256)
void attn_kernel(const float* __restrict__ Qw, const float* __restrict__ Kw,
                 const float* __restrict__ Vw, float* __restrict__ AO)
{
    __shared__ float Ks[KT][68];
    __shared__ float Vs[KT][68];
    __shared__ float Ps[QT][68];

    const int t  = threadIdx.x;
    const int bh = blockIdx.y;
    const int q0 = blockIdx.x * QT;

    const float* Qp = Qw + (size_t)bh * SEQ * HD;
    const float* Kp = Kw + (size_t)bh * SEQ * HD;
    const float* Vp = Vw + (size_t)bh * SEQ * HD;

    const int r = t >> 3;  // 0..31
    const int u = t & 7;   // 0..7

    // Q row (already scaled by 1/8) in registers; 8 lanes/row load redundantly.
    float4 qv[16];
    {
        const float* qrow = Qp + (size_t)(q0 + r) * HD;
#pragma unroll
        for (int i = 0; i < 16; ++i) qv[i] = *(const float4*)(qrow + 4 * i);
    }

    float oacc[8] = {0, 0, 0, 0, 0, 0, 0, 0};
    float m_run = -3.0e38f;
    float l_run = 0.0f;

    for (int k0 = 0; k0 < SEQ; k0 += KT) {
        // Stage K,V tiles (64x64 each): 1024 float4 / 256 threads = 4 apiece.
#pragma unroll
        for (int s = 0; s < 4; ++s) {
            const int idx = t + 256 * s;       // 0..1023
            const int row = idx >> 4;          // 0..63
            const int c4  = (idx & 15) * 4;    // 0..60
            float4 kv = *(const float4*)(Kp + (size_t)(k0 + row) * HD + c4);
            float4 vv = *(const float4*)(Vp + (size_t)(k0 + row) * HD + c4);
            *(float4*)(&Ks[row][c4]) = kv;
            *(float4*)(&Vs[row][c4]) = vv;
        }
        __syncthreads();

        // Scores for cols c = u + 8j
        float sv[8];
#pragma unroll
        for (int j = 0; j < 8; ++j) {
            const int c = u + 8 * j;
            float s_acc = 0.0f;
#pragma unroll
            for (int i = 0; i < 16; ++i) {
                const float4 kk = *(const float4*)(&Ks[c][4 * i]);
                s_acc = fmaf(qv[i].x, kk.x, s_acc);
                s_acc = fmaf(qv[i].y, kk.y, s_acc);
                s_acc = fmaf(qv[i].z, kk.z, s_acc);
                s_acc = fmaf(qv[i].w, kk.w, s_acc);
            }
            sv[j] = s_acc;
        }

        // Online softmax: row reduce across the 8 lanes of this row group.
        float mx = sv[0];
#pragma unroll
        for (int j = 1; j < 8; ++j) mx = fmaxf(mx, sv[j]);
        mx = fmaxf(mx, __shfl_xor(mx, 1));
        mx = fmaxf(mx, __shfl_xor(mx, 2));
        mx = fmaxf(mx, __shfl_xor(mx, 4));

        const float m_new = fmaxf(m_run, mx);
        const float scale = __expf(m_run - m_new);

        float pv[8];
        float ps = 0.0f;
#pragma unroll
        for (int j = 0; j < 8; ++j) {
            pv[j] = __expf(sv[j] - m_new);
            ps += pv[j];
        }
        ps += __shfl_xor(ps, 1);
        ps += __shfl_xor(ps, 2);
        ps += __shfl_xor(ps, 4);

        l_run = l_run * scale + ps;
        m_run = m_new;
#pragma unroll
        for (int jj = 0; jj < 8; ++jj) oacc[jj] *= scale;

#pragma unroll
        for (int j = 0; j < 8; ++j) Ps[r][u + 8 * j] = pv[j];
        __syncthreads();

        // O[r][u*8+jj] += sum_c P[r][c] * V[c][u*8+jj]
#pragma unroll 8
        for (int c = 0; c < KT; ++c) {
            const float p = Ps[r][c];
            const float4 v0 = *(const float4*)(&Vs[c][u * 8]);
            const float4 v1 = *(const float4*)(&Vs[c][u * 8 + 4]);
            oacc[0] = fmaf(p, v0.x, oacc[0]);
            oacc[1] = fmaf(p, v0.y, oacc[1]);
            oacc[2] = fmaf(p, v0.z, oacc[2]);
            oacc[3] = fmaf(p, v0.w, oacc[3]);
            oacc[4] = fmaf(p, v1.x, oacc[4]);
            oacc[5] = fmaf(p, v1.y, oacc[5]);
            oacc[6] = fmaf(p, v1.z, oacc[6]);
            oacc[7] = fmaf(p, v1.w, oacc[7]);
        }
        __syncthreads();
    }

    const float inv = 1.0f / l_run;
    const int b = bh >> 4;
    const int h = bh & 15;
    float* op = AO + ((size_t)b * SEQ + q0 + r) * D_MODEL + h * HD + u * 8;
    *(float4*)(op)     = make_float4(oacc[0] * inv, oacc[1] * inv,
                                     oacc[2] * inv, oacc[3] * inv);
    *(float4*)(op + 4) = make_float4(oacc[4] * inv, oacc[5] * inv,
                                     oacc[6] * inv, oacc[7] * inv);
}

// ---------------------------------------------------------------------------
extern "C" void kernel_launch(void* const* d_in, const int* in_sizes, int n_in,
                              void* d_out, int out_size, void* d_ws, size_t ws_size,
                              hipStream_t stream)
{
    const float* x      = (const float*)d_in[0];  // (2, 2048, 1024)
    const float* w_qkv  = (const float*)d_in[1];  // (1024, 3072)
    const float* w_proj = (const float*)d_in[2];  // (1024, 1024)
    float* out = (float*)d_out;                   // (2, 2048, 1024)

    const size_t per = (size_t)BSZ * NH * SEQ * HD;  // 4 Mi floats = 16 MB
    float* Qw = (float*)d_ws;
    float* Kw = Qw + per;
    float* Vw = Kw + per;
    float* AO = Vw + per;   // [B][T][D] attention output

    dim3 blk(256);

    // 1) QKV = X @ Wqkv, scattered into head-major Q/K/V (Q pre-scaled)
    gemm128<0><<<dim3(3 * D_MODEL / 128, MTOT / 128), blk, 0, stream>>>(
        x, w_qkv, nullptr, Qw, Kw, Vw, MTOT, 3 * D_MODEL, D_MODEL);

    // 2) Flash attention -> AO [B][T][D]
    attn_kernel<<<dim3(SEQ / QT, BSZ * NH), blk, 0, stream>>>(Qw, Kw, Vw, AO);

    // 3) out = AO @ Wproj
    gemm128<1><<<dim3(D_MODEL / 128, MTOT / 128), blk, 0, stream>>>(
        AO, w_proj, out, nullptr, nullptr, nullptr, MTOT, D_MODEL, D_MODEL);
}

// Round 2
// 559.676 us; speedup vs baseline: 2.0818x; 2.0818x over previous
//
#include <hip/hip_runtime.h>
#include <hip/hip_bf16.h>
#include <cmath>

#define D_MODEL 1024
#define NH 16
#define HD 64
#define BSZ 2
#define SEQ 2048
#define MTOT (BSZ * SEQ)   // 4096

typedef short bf16x8 __attribute__((ext_vector_type(8)));
typedef float f32x4  __attribute__((ext_vector_type(4)));

__device__ __forceinline__ ushort f2bf(float x) {
    union { __hip_bfloat16 b; ushort u; } cv;
    cv.b = __float2bfloat16(x);
    return cv.u;
}

// ---------------------------------------------------------------------------
// Tiled fp32 GEMM: C[M][N] = A[M][K] * B[K][N], 128x128 tile, 8x8 per thread.
// MODE 0: QKV epilogue -> scatter BF16 into Q/K/V [B][H][T][64], Q scaled 0.125
// MODE 1: plain fp32 epilogue -> row-major out
// ---------------------------------------------------------------------------
template <int MODE>
__global__ __launch_bounds__(256)
void gemm128(const float* __restrict__ A, const float* __restrict__ B,
             float* __restrict__ outp,
             ushort* __restrict__ Qw, ushort* __restrict__ Kw, ushort* __restrict__ Vw,
             int M, int N, int Kdim)
{
    __shared__ float As[16][132];  // [k][m] (A transposed), padded
    __shared__ float Bs[16][132];  // [k][n], padded

    const int t  = threadIdx.x;
    const int m0 = blockIdx.y * 128;
    const int n0 = blockIdx.x * 128;
    const int tr = t >> 4;   // 0..15
    const int tc = t & 15;   // 0..15

    float acc[8][8];
#pragma unroll
    for (int i = 0; i < 8; ++i)
#pragma unroll
        for (int j = 0; j < 8; ++j) acc[i][j] = 0.0f;

    for (int k0 = 0; k0 < Kdim; k0 += 16) {
#pragma unroll
        for (int s = 0; s < 2; ++s) {
            const int ar = (t >> 2) + 64 * s;        // 0..127
            const int ac = (t & 3) * 4;              // 0,4,8,12
            float4 av = *(const float4*)(A + (size_t)(m0 + ar) * Kdim + k0 + ac);
            As[ac + 0][ar] = av.x;
            As[ac + 1][ar] = av.y;
            As[ac + 2][ar] = av.z;
            As[ac + 3][ar] = av.w;

            const int br = (t >> 5) + 8 * s;         // 0..15
            const int bc = (t & 31) * 4;             // 0..124
            float4 bv = *(const float4*)(B + (size_t)(k0 + br) * N + n0 + bc);
            *(float4*)(&Bs[br][bc]) = bv;
        }
        __syncthreads();

#pragma unroll
        for (int k = 0; k < 16; ++k) {
            float a[8], b[8];
            *(float4*)(a)     = *(const float4*)(&As[k][tr * 8]);
            *(float4*)(a + 4) = *(const float4*)(&As[k][tr * 8 + 4]);
            *(float4*)(b)     = *(const float4*)(&Bs[k][tc * 8]);
            *(float4*)(b + 4) = *(const float4*)(&Bs[k][tc * 8 + 4]);
#pragma unroll
            for (int i = 0; i < 8; ++i)
#pragma unroll
                for (int j = 0; j < 8; ++j)
                    acc[i][j] = fmaf(a[i], b[j], acc[i][j]);
        }
        __syncthreads();
    }

    if (MODE == 1) {
#pragma unroll
        for (int i = 0; i < 8; ++i) {
            const int m = m0 + tr * 8 + i;
            float* dst = outp + (size_t)m * N + n0 + tc * 8;
            *(float4*)(dst)     = make_float4(acc[i][0], acc[i][1], acc[i][2], acc[i][3]);
            *(float4*)(dst + 4) = make_float4(acc[i][4], acc[i][5], acc[i][6], acc[i][7]);
        }
    } else {
        const int which = n0 >> 10;
        const int h     = ((n0 & 1023) >> 6) + (tc >> 3);
        const int d0    = (tc & 7) * 8;
        ushort* dst = (which == 0) ? Qw : (which == 1) ? Kw : Vw;
        const float sc = (which == 0) ? 0.125f : 1.0f;  // 1/sqrt(64) on Q
#pragma unroll
        for (int i = 0; i < 8; ++i) {
            const int m  = m0 + tr * 8 + i;
            const int b  = m >> 11;          // / SEQ
            const int tt = m & (SEQ - 1);
            alignas(16) ushort h8[8];
#pragma unroll
            for (int j = 0; j < 8; ++j) h8[j] = f2bf(acc[i][j] * sc);
            ushort* p = dst + (((size_t)(b * NH + h) * SEQ) + tt) * HD + d0;
            *(uint4*)p = *(const uint4*)h8;
        }
    }
}

// ---------------------------------------------------------------------------
// MFMA flash attention. Block = 256 threads = 4 waves; Q tile 64 rows
// (16 per wave); K tile 64 keys staged in LDS (row-major, XOR-swizzled);
// V staged transposed Vt[d][key] (XOR-swizzled) so PV B-frags are b128 reads.
// mfma_f32_16x16x32_bf16, C/D layout: col=lane&15, row=(lane>>4)*4+reg.
// P reshaped to A-frag layout via per-wave swizzled LDS buffer.
// ---------------------------------------------------------------------------
__global__ __launch_bounds__(256)
void attn_mfma(const ushort* __restrict__ Qw, const ushort* __restrict__ Kw,
               const ushort* __restrict__ Vw, float* __restrict__ AO)
{
    __shared__ ushort Ks[64 * 64];      // K[key][d], swizzled
    __shared__ ushort Vt[64 * 64];      // V^T[d][key], swizzled
    __shared__ ushort Ps[4][16 * 64];   // per-wave P[row][key], swizzled

    const int t  = threadIdx.x;
    const int w  = t >> 6;   // wave 0..3
    const int l  = t & 63;
    const int lr = l & 15;
    const int lg = l >> 4;   // 0..3

    const int bh = blockIdx.y;
    const int q0 = blockIdx.x * 64;

    const ushort* Qp = Qw + (size_t)bh * SEQ * HD;
    const ushort* Kp = Kw + (size_t)bh * SEQ * HD;
    const ushort* Vp = Vw + (size_t)bh * SEQ * HD;

    // Q fragment: rows q0 + w*16 + lr, k-chunks kk*32 + lg*8 + (0..7)
    bf16x8 qf[2];
#pragma unroll
    for (int kk = 0; kk < 2; ++kk)
        qf[kk] = *reinterpret_cast<const bf16x8*>(
            Qp + (size_t)(q0 + w * 16 + lr) * HD + kk * 32 + lg * 8);

    f32x4 oacc[4];
#pragma unroll
    for (int nn = 0; nn < 4; ++nn) oacc[nn] = (f32x4){0.f, 0.f, 0.f, 0.f};
    float m_run[4] = {-3.0e38f, -3.0e38f, -3.0e38f, -3.0e38f};
    float l_run[4] = {0.f, 0.f, 0.f, 0.f};

    for (int k0 = 0; k0 < SEQ; k0 += 64) {
        // ---- stage K (row-major) and V (transposed), both XOR-swizzled ----
#pragma unroll
        for (int s = 0; s < 2; ++s) {
            const int c = t + 256 * s;
            {   // K: 16B per chunk, coalesced
                const int key = c >> 3, d0 = (c & 7) * 8;
                uint4 kv = *reinterpret_cast<const uint4*>(
                    Kp + (size_t)(k0 + key) * HD + d0);
                *reinterpret_cast<uint4*>(
                    (char*)Ks + ((key * 128 + d0 * 2) ^ ((key & 7) << 4))) = kv;
            }
            {   // V: load one key-row chunk, scatter transposed (b16 writes,
                // conflict-free: 64 lanes hit 64 consecutive half-words)
                const int key = c & 63, d0 = (c >> 6) * 8;
                uint4 vv = *reinterpret_cast<const uint4*>(
                    Vp + (size_t)(k0 + key) * HD + d0);
                alignas(16) ushort e8[8];
                *reinterpret_cast<uint4*>(e8) = vv;
#pragma unroll
                for (int i = 0; i < 8; ++i) {
                    const int d = d0 + i;
                    *reinterpret_cast<ushort*>(
                        (char*)Vt + ((d * 128 + key * 2) ^ ((d & 7) << 4))) = e8[i];
                }
            }
        }
        __syncthreads();

        // ---- S = Q K^T : rows=(lg*4+i), cols=n*16+lr ----
        f32x4 sacc[4];
#pragma unroll
        for (int n = 0; n < 4; ++n) {
            f32x4 acc = (f32x4){0.f, 0.f, 0.f, 0.f};
            const int krow = n * 16 + lr;
#pragma unroll
            for (int kk = 0; kk < 2; ++kk) {
                bf16x8 bf = *reinterpret_cast<const bf16x8*>(
                    (char*)Ks + ((krow * 128 + kk * 64 + lg * 16) ^ ((krow & 7) << 4)));
                acc = __builtin_amdgcn_mfma_f32_16x16x32_bf16(qf[kk], bf, acc, 0, 0, 0);
            }
            sacc[n] = acc;
        }

        // ---- online softmax (per row lg*4+i; reduce across 16 lanes) ----
#pragma unroll
        for (int i = 0; i < 4; ++i) {
            float mx = fmaxf(fmaxf(sacc[0][i], sacc[1][i]),
                             fmaxf(sacc[2][i], sacc[3][i]));
            mx = fmaxf(mx, __shfl_xor(mx, 1));
            mx = fmaxf(mx, __shfl_xor(mx, 2));
            mx = fmaxf(mx, __shfl_xor(mx, 4));
            mx = fmaxf(mx, __shfl_xor(mx, 8));
            const float m_new = fmaxf(m_run[i], mx);
            const float scale = __expf(m_run[i] - m_new);
            m_run[i] = m_new;

            float p0 = __expf(sacc[0][i] - m_new);
            float p1 = __expf(sacc[1][i] - m_new);
            float p2 = __expf(sacc[2][i] - m_new);
            float p3 = __expf(sacc[3][i] - m_new);
            float sum = (p0 + p1) + (p2 + p3);
            sum += __shfl_xor(sum, 1);
            sum += __shfl_xor(sum, 2);
            sum += __shfl_xor(sum, 4);
            sum += __shfl_xor(sum, 8);
            l_run[i] = l_run[i] * scale + sum;
#pragma unroll
            for (int nn = 0; nn < 4; ++nn) oacc[nn][i] *= scale;

            // P -> per-wave LDS (bf16, swizzled), row = lg*4+i, col = n*16+lr
            const int row = lg * 4 + i;
            char* base = (char*)Ps[w];
            *reinterpret_cast<ushort*>(base + ((row * 128 + (0 * 16 + lr) * 2) ^ ((row & 7) << 4))) = f2bf(p0);
            *reinterpret_cast<ushort*>(base + ((row * 128 + (1 * 16 + lr) * 2) ^ ((row & 7) << 4))) = f2bf(p1);
            *reinterpret_cast<ushort*>(base + ((row * 128 + (2 * 16 + lr) * 2) ^ ((row & 7) << 4))) = f2bf(p2);
            *reinterpret_cast<ushort*>(base + ((row * 128 + (3 * 16 + lr) * 2) ^ ((row & 7) << 4))) = f2bf(p3);
        }

        // wave-local write->read of Ps: ensure LDS ops drained
        asm volatile("s_waitcnt lgkmcnt(0)" ::: "memory");

        // ---- O += P V : A=P (from Ps), B=V (from Vt) ----
#pragma unroll
        for (int kc = 0; kc < 2; ++kc) {
            bf16x8 pa = *reinterpret_cast<const bf16x8*>(
                (char*)Ps[w] + ((lr * 128 + kc * 64 + lg * 16) ^ ((lr & 7) << 4)));
#pragma unroll
            for (int nn = 0; nn < 4; ++nn) {
                const int drow = nn * 16 + lr;
                bf16x8 vb = *reinterpret_cast<const bf16x8*>(
                    (char*)Vt + ((drow * 128 + kc * 64 + lg * 16) ^ ((drow & 7) << 4)));
                oacc[nn] = __builtin_amdgcn_mfma_f32_16x16x32_bf16(pa, vb, oacc[nn], 0, 0, 0);
            }
        }
        __syncthreads();
    }

    // ---- epilogue: O /= l, write fp32 AO [B][T][D] ----
    const int b = bh >> 4;
    const int h = bh & 15;
#pragma unroll
    for (int i = 0; i < 4; ++i) {
        const float inv = 1.0f / l_run[i];
        float* op = AO + ((size_t)(b * SEQ) + q0 + w * 16 + lg * 4 + i) * D_MODEL
                       + h * HD + lr;
#pragma unroll
        for (int nn = 0; nn < 4; ++nn)
            op[nn * 16] = oacc[nn][i] * inv;
    }
}

// ---------------------------------------------------------------------------
extern "C" void kernel_launch(void* const* d_in, const int* in_sizes, int n_in,
                              void* d_out, int out_size, void* d_ws, size_t ws_size,
                              hipStream_t stream)
{
    const float* x      = (const float*)d_in[0];  // (2, 2048, 1024)
    const float* w_qkv  = (const float*)d_in[1];  // (1024, 3072)
    const float* w_proj = (const float*)d_in[2];  // (1024, 1024)
    float* out = (float*)d_out;                   // (2, 2048, 1024)

    const size_t per = (size_t)BSZ * NH * SEQ * HD;  // 4 Mi elements
    ushort* Qw = (ushort*)d_ws;                      // bf16, 8 MB each
    ushort* Kw = Qw + per;
    ushort* Vw = Kw + per;
    float*  AO = (float*)(Vw + per);                 // fp32 [B][T][D], 16 MB

    dim3 blk(256);

    // 1) QKV = X @ Wqkv -> bf16 head-major Q/K/V (Q pre-scaled by 0.125)
    gemm128<0><<<dim3(3 * D_MODEL / 128, MTOT / 128), blk, 0, stream>>>(
        x, w_qkv, nullptr, Qw, Kw, Vw, MTOT, 3 * D_MODEL, D_MODEL);

    // 2) MFMA flash attention -> AO [B][T][D] fp32
    attn_mfma<<<dim3(SEQ / 64, BSZ * NH), blk, 0, stream>>>(Qw, Kw, Vw, AO);

    // 3) out = AO @ Wproj (fp32 VALU GEMM)
    gemm128<1><<<dim3(D_MODEL / 128, MTOT / 128), blk, 0, stream>>>(
        AO, w_proj, out, nullptr, nullptr, nullptr, MTOT, D_MODEL, D_MODEL);
}

// Round 3
// 220.767 us; speedup vs baseline: 5.2777x; 2.5351x over previous
//
#include <hip/hip_runtime.h>
#include <hip/hip_bf16.h>
#include <cmath>

#define D_MODEL 1024
#define NH 16
#define HD 64
#define BSZ 2
#define SEQ 2048
#define MTOT (BSZ * SEQ)   // 4096

typedef _Float16 f16x8 __attribute__((ext_vector_type(8)));
typedef float    f32x4 __attribute__((ext_vector_type(4)));

__device__ __forceinline__ ushort f2h(float x) {
    union { _Float16 h; ushort u; } cv;
    cv.h = (_Float16)x;
    return cv.u;
}

// async global->LDS, 16B per lane; lds base must be wave-uniform
__device__ __forceinline__ void gload_lds16(const ushort* g, ushort* l) {
    __builtin_amdgcn_global_load_lds(
        (const __attribute__((address_space(1))) void*)g,
        (__attribute__((address_space(3))) void*)l, 16, 0, 0);
}

// ---------------------------------------------------------------------------
// fp32 -> f16 cast, 8 elems/thread
// ---------------------------------------------------------------------------
__global__ __launch_bounds__(256)
void cast8(const float* __restrict__ in, ushort* __restrict__ out, int n)
{
    const int i = (blockIdx.x * 256 + threadIdx.x) * 8;
    if (i >= n) return;
    float4 a = *(const float4*)(in + i);
    float4 b = *(const float4*)(in + i + 4);
    alignas(16) ushort h8[8];
    h8[0] = f2h(a.x); h8[1] = f2h(a.y); h8[2] = f2h(a.z); h8[3] = f2h(a.w);
    h8[4] = f2h(b.x); h8[5] = f2h(b.y); h8[6] = f2h(b.z); h8[7] = f2h(b.w);
    *(uint4*)(out + i) = *(const uint4*)h8;
}

// ---------------------------------------------------------------------------
// transpose + cast: in[R][C] fp32 -> out[C][R] f16.  32x32 LDS tile.
// ---------------------------------------------------------------------------
__global__ __launch_bounds__(256)
void transpose_cast(const float* __restrict__ in, ushort* __restrict__ out,
                    int R, int C)
{
    __shared__ float tile[32][33];
    const int t  = threadIdx.x;
    const int r0 = blockIdx.y * 32, c0 = blockIdx.x * 32;
    const int tr = t >> 5, tc = t & 31;   // 8 x 32
#pragma unroll
    for (int s = 0; s < 4; ++s)
        tile[tr + 8 * s][tc] = in[(size_t)(r0 + tr + 8 * s) * C + c0 + tc];
    __syncthreads();
#pragma unroll
    for (int s = 0; s < 4; ++s)
        out[(size_t)(c0 + tr + 8 * s) * R + r0 + tc] = f2h(tile[tc][tr + 8 * s]);
}

// ---------------------------------------------------------------------------
// MFMA GEMM (m97 structure): C[M][N] = A[M][1024] * Bt[N][1024]^T, f16 in,
// fp32 accum. 128x128 block tile, 4 waves (2x2), BK=64, global_load_lds x16.
// MODE 0: QKV scatter epilogue -> f16 Q/K/V [B][H][T][64], Q scaled 0.125
// MODE 1: fp32 row-major out [M][N]
// ---------------------------------------------------------------------------
template <int MODE>
__global__ __launch_bounds__(256)
void gemm_mfma(const ushort* __restrict__ A, const ushort* __restrict__ Bt,
               float* __restrict__ outp,
               ushort* __restrict__ Qw, ushort* __restrict__ Kw,
               ushort* __restrict__ Vw, int N)
{
    __shared__ ushort As[128 * 64];   // [row][k] linear, 16 KB
    __shared__ ushort Bs[128 * 64];

    const int t  = threadIdx.x;
    const int w  = t >> 6;            // wave 0..3
    const int l  = t & 63;
    const int lr = l & 15;
    const int lg = l >> 4;
    const int wr = w >> 1, wc = w & 1;
    const int m0 = blockIdx.y * 128, n0 = blockIdx.x * 128;

    const int srow = l >> 3;          // staging: lane -> row 0..7
    const int scol = (l & 7) * 8;     // lane -> k-offset (elems)

    const ushort* Ab = A  + (size_t)m0 * 1024;
    const ushort* Bb = Bt + (size_t)n0 * 1024;

    f32x4 acc[4][4];
#pragma unroll
    for (int i = 0; i < 4; ++i)
#pragma unroll
        for (int j = 0; j < 4; ++j) acc[i][j] = (f32x4){0.f, 0.f, 0.f, 0.f};

    for (int k0 = 0; k0 < 1024; k0 += 64) {
        // stage A,B tiles: wave w loads rows (w*4+i)*8 .. +8 of each
#pragma unroll
        for (int i = 0; i < 4; ++i) {
            const int r8 = (w * 4 + i) * 8;
            gload_lds16(Ab + (size_t)(r8 + srow) * 1024 + k0 + scol, &As[r8 * 64]);
            gload_lds16(Bb + (size_t)(r8 + srow) * 1024 + k0 + scol, &Bs[r8 * 64]);
        }
        __syncthreads();   // drains vmcnt (global_load_lds) + lgkm

#pragma unroll
        for (int kk = 0; kk < 2; ++kk) {
            f16x8 af[4], bf[4];
#pragma unroll
            for (int m = 0; m < 4; ++m)
                af[m] = *(const f16x8*)&As[(wr * 64 + m * 16 + lr) * 64 + kk * 32 + lg * 8];
#pragma unroll
            for (int n = 0; n < 4; ++n)
                bf[n] = *(const f16x8*)&Bs[(wc * 64 + n * 16 + lr) * 64 + kk * 32 + lg * 8];
#pragma unroll
            for (int m = 0; m < 4; ++m)
#pragma unroll
                for (int n = 0; n < 4; ++n)
                    acc[m][n] = __builtin_amdgcn_mfma_f32_16x16x32_f16(
                        af[m], bf[n], acc[m][n], 0, 0, 0);
        }
        __syncthreads();
    }

    if (MODE == 1) {
#pragma unroll
        for (int mf = 0; mf < 4; ++mf) {
            const int row = m0 + wr * 64 + mf * 16 + lg * 4;
#pragma unroll
            for (int nf = 0; nf < 4; ++nf) {
                const int col = n0 + wc * 64 + nf * 16 + lr;
#pragma unroll
                for (int i = 0; i < 4; ++i)
                    outp[(size_t)(row + i) * N + col] = acc[mf][nf][i];
            }
        }
    } else {
#pragma unroll
        for (int mf = 0; mf < 4; ++mf) {
            const int row = m0 + wr * 64 + mf * 16 + lg * 4;   // +i
            const int b   = row >> 11;
            const int tt0 = row & (SEQ - 1);
#pragma unroll
            for (int nf = 0; nf < 4; ++nf) {
                const int col   = n0 + wc * 64 + nf * 16 + lr;
                const int which = col >> 10;
                const int h     = (col >> 6) & 15;
                const int d     = col & 63;
                ushort* dst = (which == 0) ? Qw : (which == 1) ? Kw : Vw;
                const float sc = (which == 0) ? 0.125f : 1.0f;  // 1/sqrt(64)
#pragma unroll
                for (int i = 0; i < 4; ++i)
                    dst[((size_t)(b * NH + h) * SEQ + tt0 + i) * HD + d] =
                        f2h(acc[mf][nf][i] * sc);
            }
        }
    }
}

// ---------------------------------------------------------------------------
// MFMA flash attention (f16). Block = 4 waves; Q tile 64 rows (16/wave);
// K tile 64 keys in LDS (row-major, XOR-swizzled); V transposed Vt[d][key].
// mfma_f32_16x16x32_f16, C/D layout: col=lane&15, row=(lane>>4)*4+reg.
// ---------------------------------------------------------------------------
__global__ __launch_bounds__(256)
void attn_mfma(const ushort* __restrict__ Qw, const ushort* __restrict__ Kw,
               const ushort* __restrict__ Vw, ushort* __restrict__ AO)
{
    __shared__ ushort Ks[64 * 64];      // K[key][d], swizzled
    __shared__ ushort Vt[64 * 64];      // V^T[d][key], swizzled
    __shared__ ushort Ps[4][16 * 64];   // per-wave P[row][key], swizzled

    const int t  = threadIdx.x;
    const int w  = t >> 6;
    const int l  = t & 63;
    const int lr = l & 15;
    const int lg = l >> 4;

    const int bh = blockIdx.y;
    const int q0 = blockIdx.x * 64;

    const ushort* Qp = Qw + (size_t)bh * SEQ * HD;
    const ushort* Kp = Kw + (size_t)bh * SEQ * HD;
    const ushort* Vp = Vw + (size_t)bh * SEQ * HD;

    f16x8 qf[2];
#pragma unroll
    for (int kk = 0; kk < 2; ++kk)
        qf[kk] = *reinterpret_cast<const f16x8*>(
            Qp + (size_t)(q0 + w * 16 + lr) * HD + kk * 32 + lg * 8);

    f32x4 oacc[4];
#pragma unroll
    for (int nn = 0; nn < 4; ++nn) oacc[nn] = (f32x4){0.f, 0.f, 0.f, 0.f};
    float m_run[4] = {-3.0e38f, -3.0e38f, -3.0e38f, -3.0e38f};
    float l_run[4] = {0.f, 0.f, 0.f, 0.f};

    for (int k0 = 0; k0 < SEQ; k0 += 64) {
#pragma unroll
        for (int s = 0; s < 2; ++s) {
            const int c = t + 256 * s;
            {   // K row-major
                const int key = c >> 3, d0 = (c & 7) * 8;
                uint4 kv = *reinterpret_cast<const uint4*>(
                    Kp + (size_t)(k0 + key) * HD + d0);
                *reinterpret_cast<uint4*>(
                    (char*)Ks + ((key * 128 + d0 * 2) ^ ((key & 7) << 4))) = kv;
            }
            {   // V transposed scatter
                const int key = c & 63, d0 = (c >> 6) * 8;
                uint4 vv = *reinterpret_cast<const uint4*>(
                    Vp + (size_t)(k0 + key) * HD + d0);
                alignas(16) ushort e8[8];
                *reinterpret_cast<uint4*>(e8) = vv;
#pragma unroll
                for (int i = 0; i < 8; ++i) {
                    const int d = d0 + i;
                    *reinterpret_cast<ushort*>(
                        (char*)Vt + ((d * 128 + key * 2) ^ ((d & 7) << 4))) = e8[i];
                }
            }
        }
        __syncthreads();

        // S = Q K^T
        f32x4 sacc[4];
#pragma unroll
        for (int n = 0; n < 4; ++n) {
            f32x4 acc = (f32x4){0.f, 0.f, 0.f, 0.f};
            const int krow = n * 16 + lr;
#pragma unroll
            for (int kk = 0; kk < 2; ++kk) {
                f16x8 bf = *reinterpret_cast<const f16x8*>(
                    (char*)Ks + ((krow * 128 + kk * 64 + lg * 16) ^ ((krow & 7) << 4)));
                acc = __builtin_amdgcn_mfma_f32_16x16x32_f16(qf[kk], bf, acc, 0, 0, 0);
            }
            sacc[n] = acc;
        }

        // online softmax
#pragma unroll
        for (int i = 0; i < 4; ++i) {
            float mx = fmaxf(fmaxf(sacc[0][i], sacc[1][i]),
                             fmaxf(sacc[2][i], sacc[3][i]));
            mx = fmaxf(mx, __shfl_xor(mx, 1));
            mx = fmaxf(mx, __shfl_xor(mx, 2));
            mx = fmaxf(mx, __shfl_xor(mx, 4));
            mx = fmaxf(mx, __shfl_xor(mx, 8));
            const float m_new = fmaxf(m_run[i], mx);
            const float scale = __expf(m_run[i] - m_new);
            m_run[i] = m_new;

            float p0 = __expf(sacc[0][i] - m_new);
            float p1 = __expf(sacc[1][i] - m_new);
            float p2 = __expf(sacc[2][i] - m_new);
            float p3 = __expf(sacc[3][i] - m_new);
            float sum = (p0 + p1) + (p2 + p3);
            sum += __shfl_xor(sum, 1);
            sum += __shfl_xor(sum, 2);
            sum += __shfl_xor(sum, 4);
            sum += __shfl_xor(sum, 8);
            l_run[i] = l_run[i] * scale + sum;
#pragma unroll
            for (int nn = 0; nn < 4; ++nn) oacc[nn][i] *= scale;

            const int row = lg * 4 + i;
            char* base = (char*)Ps[w];
            *reinterpret_cast<ushort*>(base + ((row * 128 + (0 * 16 + lr) * 2) ^ ((row & 7) << 4))) = f2h(p0);
            *reinterpret_cast<ushort*>(base + ((row * 128 + (1 * 16 + lr) * 2) ^ ((row & 7) << 4))) = f2h(p1);
            *reinterpret_cast<ushort*>(base + ((row * 128 + (2 * 16 + lr) * 2) ^ ((row & 7) << 4))) = f2h(p2);
            *reinterpret_cast<ushort*>(base + ((row * 128 + (3 * 16 + lr) * 2) ^ ((row & 7) << 4))) = f2h(p3);
        }

        asm volatile("s_waitcnt lgkmcnt(0)" ::: "memory");

        // O += P V
#pragma unroll
        for (int kc = 0; kc < 2; ++kc) {
            f16x8 pa = *reinterpret_cast<const f16x8*>(
                (char*)Ps[w] + ((lr * 128 + kc * 64 + lg * 16) ^ ((lr & 7) << 4)));
#pragma unroll
            for (int nn = 0; nn < 4; ++nn) {
                const int drow = nn * 16 + lr;
                f16x8 vb = *reinterpret_cast<const f16x8*>(
                    (char*)Vt + ((drow * 128 + kc * 64 + lg * 16) ^ ((drow & 7) << 4)));
                oacc[nn] = __builtin_amdgcn_mfma_f32_16x16x32_f16(pa, vb, oacc[nn], 0, 0, 0);
            }
        }
        __syncthreads();
    }

    // epilogue: O /= l, write f16 AO [B][T][D]
    const int b = bh >> 4;
    const int h = bh & 15;
#pragma unroll
    for (int i = 0; i < 4; ++i) {
        const float inv = 1.0f / l_run[i];
        ushort* op = AO + ((size_t)(b * SEQ) + q0 + w * 16 + lg * 4 + i) * D_MODEL
                        + h * HD + lr;
#pragma unroll
        for (int nn = 0; nn < 4; ++nn)
            op[nn * 16] = f2h(oacc[nn][i] * inv);
    }
}

// ---------------------------------------------------------------------------
extern "C" void kernel_launch(void* const* d_in, const int* in_sizes, int n_in,
                              void* d_out, int out_size, void* d_ws, size_t ws_size,
                              hipStream_t stream)
{
    const float* x      = (const float*)d_in[0];  // (2, 2048, 1024)
    const float* w_qkv  = (const float*)d_in[1];  // (1024, 3072)
    const float* w_proj = (const float*)d_in[2];  // (1024, 1024)
    float* out = (float*)d_out;                   // (2, 2048, 1024) fp32

    // f16 workspace layout (elements)
    ushort* Xh  = (ushort*)d_ws;                        // 4M
    ushort* WqT = Xh  + (size_t)MTOT * D_MODEL;         // 3M  [3072][1024]
    ushort* WpT = WqT + (size_t)3 * D_MODEL * D_MODEL;  // 1M  [1024][1024]
    ushort* Qw  = WpT + (size_t)D_MODEL * D_MODEL;      // 4M  [B][H][T][64]
    ushort* Kw  = Qw  + (size_t)MTOT * D_MODEL;
    ushort* Vw  = Kw  + (size_t)MTOT * D_MODEL;
    ushort* AOh = Vw  + (size_t)MTOT * D_MODEL;         // 4M  [B][T][D]

    dim3 blk(256);

    // 0) casts: x -> f16; weights -> transposed f16 [N][K]
    cast8<<<dim3(MTOT * D_MODEL / (8 * 256)), blk, 0, stream>>>(x, Xh, MTOT * D_MODEL);
    transpose_cast<<<dim3(3 * D_MODEL / 32, D_MODEL / 32), blk, 0, stream>>>(
        w_qkv, WqT, D_MODEL, 3 * D_MODEL);
    transpose_cast<<<dim3(D_MODEL / 32, D_MODEL / 32), blk, 0, stream>>>(
        w_proj, WpT, D_MODEL, D_MODEL);

    // 1) QKV = X @ Wqkv (MFMA) -> f16 head-major Q/K/V, Q pre-scaled
    gemm_mfma<0><<<dim3(3 * D_MODEL / 128, MTOT / 128), blk, 0, stream>>>(
        Xh, WqT, nullptr, Qw, Kw, Vw, 3 * D_MODEL);

    // 2) MFMA flash attention -> f16 AO [B][T][D]
    attn_mfma<<<dim3(SEQ / 64, BSZ * NH), blk, 0, stream>>>(Qw, Kw, Vw, AOh);

    // 3) out = AO @ Wproj (MFMA) -> fp32 d_out
    gemm_mfma<1><<<dim3(D_MODEL / 128, MTOT / 128), blk, 0, stream>>>(
        AOh, WpT, out, nullptr, nullptr, nullptr, D_MODEL);
}

// Round 5
// 158.507 us; speedup vs baseline: 7.3507x; 1.3928x over previous
//
#include <hip/hip_runtime.h>
#include <hip/hip_bf16.h>
#include <cmath>

#define D_MODEL 1024
#define NH 16
#define HD 64
#define BSZ 2
#define SEQ 2048
#define MTOT (BSZ * SEQ)   // 4096

typedef _Float16 f16x8 __attribute__((ext_vector_type(8)));
typedef __fp16   fp16x2 __attribute__((ext_vector_type(2)));  // cvt_pkrtz result type
typedef float    f32x4  __attribute__((ext_vector_type(4)));
typedef float    f32x16 __attribute__((ext_vector_type(16)));

// Q pre-scale: (1/sqrt(64)) * log2(e)  -> softmax runs in exp2 domain (1 instr)
#define QSCALE 0.18033688011112042f

__device__ __forceinline__ ushort f2h(float x) {
    union { _Float16 h; ushort u; } cv;
    cv.h = (_Float16)x;
    return cv.u;
}
__device__ __forceinline__ uint pkh(float a, float b) {   // pack 2 f32 -> 2 f16
    union { fp16x2 h; uint u; } cv;
    cv.h = __builtin_amdgcn_cvt_pkrtz(a, b);
    return cv.u;
}
__device__ __forceinline__ float fexp2(float x) {
    float r; asm("v_exp_f32 %0, %1" : "=v"(r) : "v"(x)); return r;
}
// async global->LDS, 16B/lane; lds base wave-uniform, data lands at base+lane*16
__device__ __forceinline__ void gload_lds16(const ushort* g, ushort* l) {
    __builtin_amdgcn_global_load_lds(
        (const __attribute__((address_space(1))) void*)g,
        (__attribute__((address_space(3))) void*)l, 16, 0, 0);
}

// ---------------------------------------------------------------------------
// fp32 -> f16 cast, 8 elems/thread
// ---------------------------------------------------------------------------
__global__ __launch_bounds__(256)
void cast8(const float* __restrict__ in, ushort* __restrict__ out, int n)
{
    const int i = (blockIdx.x * 256 + threadIdx.x) * 8;
    if (i >= n) return;
    float4 a = *(const float4*)(in + i);
    float4 b = *(const float4*)(in + i + 4);
    alignas(16) ushort h8[8];
    h8[0] = f2h(a.x); h8[1] = f2h(a.y); h8[2] = f2h(a.z); h8[3] = f2h(a.w);
    h8[4] = f2h(b.x); h8[5] = f2h(b.y); h8[6] = f2h(b.z); h8[7] = f2h(b.w);
    *(uint4*)(out + i) = *(const uint4*)h8;
}

// ---------------------------------------------------------------------------
// transpose + cast: in[R][C] fp32 -> out[C][R] f16.  32x32 LDS tile.
// ---------------------------------------------------------------------------
__global__ __launch_bounds__(256)
void transpose_cast(const float* __restrict__ in, ushort* __restrict__ out,
                    int R, int C)
{
    __shared__ float tile[32][33];
    const int t  = threadIdx.x;
    const int r0 = blockIdx.y * 32, c0 = blockIdx.x * 32;
    const int tr = t >> 5, tc = t & 31;   // 8 x 32
#pragma unroll
    for (int s = 0; s < 4; ++s)
        tile[tr + 8 * s][tc] = in[(size_t)(r0 + tr + 8 * s) * C + c0 + tc];
    __syncthreads();
#pragma unroll
    for (int s = 0; s < 4; ++s)
        out[(size_t)(c0 + tr + 8 * s) * R + r0 + tc] = f2h(tile[tc][tr + 8 * s]);
}

// ---------------------------------------------------------------------------
// MFMA GEMM (m97 structure): C[M][N] = A[M][1024] * Bt[N][1024]^T, f16 in,
// fp32 accum. 128x128 tile, 4 waves (2x2), BK=64, global_load_lds x16.
// MODE 0: QKV scatter -> f16 Q/K/V [B][H][T][64], Q scaled by QSCALE
// MODE 1: fp32 row-major out [M][N]
// ---------------------------------------------------------------------------
template <int MODE>
__global__ __launch_bounds__(256)
void gemm_mfma(const ushort* __restrict__ A, const ushort* __restrict__ Bt,
               float* __restrict__ outp,
               ushort* __restrict__ Qw, ushort* __restrict__ Kw,
               ushort* __restrict__ Vw, int N)
{
    __shared__ ushort As[128 * 64];
    __shared__ ushort Bs[128 * 64];

    const int t  = threadIdx.x;
    const int w  = t >> 6;
    const int l  = t & 63;
    const int lr = l & 15;
    const int lg = l >> 4;
    const int wr = w >> 1, wc = w & 1;
    const int m0 = blockIdx.y * 128, n0 = blockIdx.x * 128;

    const int srow = l >> 3;
    const int scol = (l & 7) * 8;

    const ushort* Ab = A  + (size_t)m0 * 1024;
    const ushort* Bb = Bt + (size_t)n0 * 1024;

    f32x4 acc[4][4];
#pragma unroll
    for (int i = 0; i < 4; ++i)
#pragma unroll
        for (int j = 0; j < 4; ++j) acc[i][j] = (f32x4){0.f, 0.f, 0.f, 0.f};

    for (int k0 = 0; k0 < 1024; k0 += 64) {
#pragma unroll
        for (int i = 0; i < 4; ++i) {
            const int r8 = (w * 4 + i) * 8;
            gload_lds16(Ab + (size_t)(r8 + srow) * 1024 + k0 + scol, &As[r8 * 64]);
            gload_lds16(Bb + (size_t)(r8 + srow) * 1024 + k0 + scol, &Bs[r8 * 64]);
        }
        __syncthreads();

#pragma unroll
        for (int kk = 0; kk < 2; ++kk) {
            f16x8 af[4], bf[4];
#pragma unroll
            for (int m = 0; m < 4; ++m)
                af[m] = *(const f16x8*)&As[(wr * 64 + m * 16 + lr) * 64 + kk * 32 + lg * 8];
#pragma unroll
            for (int n = 0; n < 4; ++n)
                bf[n] = *(const f16x8*)&Bs[(wc * 64 + n * 16 + lr) * 64 + kk * 32 + lg * 8];
#pragma unroll
            for (int m = 0; m < 4; ++m)
#pragma unroll
                for (int n = 0; n < 4; ++n)
                    acc[m][n] = __builtin_amdgcn_mfma_f32_16x16x32_f16(
                        af[m], bf[n], acc[m][n], 0, 0, 0);
        }
        __syncthreads();
    }

    if (MODE == 1) {
#pragma unroll
        for (int mf = 0; mf < 4; ++mf) {
            const int row = m0 + wr * 64 + mf * 16 + lg * 4;
#pragma unroll
            for (int nf = 0; nf < 4; ++nf) {
                const int col = n0 + wc * 64 + nf * 16 + lr;
#pragma unroll
                for (int i = 0; i < 4; ++i)
                    outp[(size_t)(row + i) * N + col] = acc[mf][nf][i];
            }
        }
    } else {
#pragma unroll
        for (int mf = 0; mf < 4; ++mf) {
            const int row = m0 + wr * 64 + mf * 16 + lg * 4;
            const int b   = row >> 11;
            const int tt0 = row & (SEQ - 1);
#pragma unroll
            for (int nf = 0; nf < 4; ++nf) {
                const int col   = n0 + wc * 64 + nf * 16 + lr;
                const int which = col >> 10;
                const int h     = (col >> 6) & 15;
                const int d     = col & 63;
                ushort* dst = (which == 0) ? Qw : (which == 1) ? Kw : Vw;
                const float sc = (which == 0) ? QSCALE : 1.0f;
#pragma unroll
                for (int i = 0; i < 4; ++i)
                    dst[((size_t)(b * NH + h) * SEQ + tt0 + i) * HD + d] =
                        f2h(acc[mf][nf][i] * sc);
            }
        }
    }
}

// ---------------------------------------------------------------------------
// Swapped-operand MFMA flash attention (m214 structure, adapted D=64).
// Block = 4 waves x 32 q-rows = 128 q.  KV tile = 64 keys, double-buffered.
//   S^T = mfma(K, Q):  C col = lane&31 = q  -> lane holds 32 scores of ONE q
//   softmax fully in-lane + one shfl_xor(32)
//   P^T frags assembled in-register (cvt_pkrtz + shfl_xor(32) + select)
//   O^T = mfma(V^T, P^T): col = q -> rescale is lane-uniform
// C/D layout (m74/m101): col=lane&31, row=(reg&3)+8*(reg>>2)+4*(lane>>5).
// A/B k-slot: k = (lane>>5)*8 + j  (shared by both operands -> cancels).
// ---------------------------------------------------------------------------
__global__ __launch_bounds__(256)
void attn_mfma2(const ushort* __restrict__ Qw, const ushort* __restrict__ Kw,
                const ushort* __restrict__ Vw, ushort* __restrict__ AO)
{
    __shared__ ushort Ks[2][64 * 64];   // K[key][d], XOR-swizzled units
    __shared__ ushort Vt[2][64 * 64];   // V^T[d][key], XOR-swizzled units

    const int t  = threadIdx.x;
    const int w  = t >> 6;
    const int l  = t & 63;
    const int q  = l & 31;    // lane's q column
    const int hi = l >> 5;    // 0/1

    const int bh = blockIdx.y;
    const int q0 = blockIdx.x * 128 + w * 32;

    const ushort* Qp = Qw + (size_t)bh * SEQ * HD;
    const ushort* Kp = Kw + (size_t)bh * SEQ * HD;
    const ushort* Vp = Vw + (size_t)bh * SEQ * HD;

    // Q B-frags: qf[kc] = Q[q0+q][kc*16 + hi*8 + (0..7)]
    f16x8 qf[4];
#pragma unroll
    for (int kc = 0; kc < 4; ++kc)
        qf[kc] = *(const f16x8*)(Qp + (size_t)(q0 + q) * HD + kc * 16 + hi * 8);

    f32x16 oacc[2];
#pragma unroll
    for (int db = 0; db < 2; ++db)
#pragma unroll
        for (int r = 0; r < 16; ++r) oacc[db][r] = 0.f;
    float m_run = -3.0e38f, l_run = 0.f;

    // --- staging: K via gload_lds (linear dest, inverse-swizzled source) ---
    auto stageK = [&](int buf, int k0) {
#pragma unroll
        for (int s = 0; s < 2; ++s) {
            const int c    = w * 64 + l + 256 * s;      // 16B chunk id
            const int row  = c >> 3;
            const int unit = (c & 7) ^ (row & 7);       // pre-swizzled source
            gload_lds16(Kp + (size_t)(k0 + row) * HD + unit * 8,
                        &Ks[buf][(w * 64 + 256 * s) * 8]);
        }
    };
    // V: reg-staged, transposed+swizzled scatter (T14 split: load early, write late)
    const int vkey = l;
    auto loadV = [&](int k0, uint4& r0, uint4& r1) {
        r0 = *(const uint4*)(Vp + (size_t)(k0 + vkey) * HD + w * 8);
        r1 = *(const uint4*)(Vp + (size_t)(k0 + vkey) * HD + (w + 4) * 8);
    };
    auto writeV = [&](int buf, uint4 r0, uint4 r1) {
        alignas(16) ushort e8[8];
        *(uint4*)e8 = r0;
#pragma unroll
        for (int i = 0; i < 8; ++i) {
            const int d = w * 8 + i;
            *(ushort*)((char*)Vt[buf] + (d * 128 + ((vkey * 2) ^ (i << 4)))) = e8[i];
        }
        *(uint4*)e8 = r1;
#pragma unroll
        for (int i = 0; i < 8; ++i) {
            const int d = (w + 4) * 8 + i;
            *(ushort*)((char*)Vt[buf] + (d * 128 + ((vkey * 2) ^ (i << 4)))) = e8[i];
        }
    };

    // prologue: stage tile 0 into buf 0
    {
        uint4 r0, r1;
        stageK(0, 0);
        loadV(0, r0, r1);
        writeV(0, r0, r1);
    }
    __syncthreads();

    int cur = 0;
    for (int kt = 0; kt < SEQ / 64; ++kt) {
        const bool pf = (kt + 1 < SEQ / 64);
        uint4 vr0, vr1;
        if (pf) {                       // issue next-tile loads before compute
            stageK(cur ^ 1, (kt + 1) * 64);
            loadV((kt + 1) * 64, vr0, vr1);
        }

        // ---- S^T = K . Q^T ----
        f32x16 sacc[2];
#pragma unroll
        for (int kb = 0; kb < 2; ++kb) {
            f32x16 a;
#pragma unroll
            for (int r = 0; r < 16; ++r) a[r] = 0.f;
            const int row = kb * 32 + q;
            const int swz = (row & 7) << 4;
#pragma unroll
            for (int kc = 0; kc < 4; ++kc) {
                f16x8 kf = *(const f16x8*)(
                    (const char*)Ks[cur] + row * 128 + ((kc * 32 + hi * 16) ^ swz));
                a = __builtin_amdgcn_mfma_f32_32x32x16_f16(kf, qf[kc], a, 0, 0, 0);
            }
            sacc[kb] = a;
        }

        // ---- in-lane online softmax (exp2 domain), full row = own + lane^32 ----
        float tm[16];
#pragma unroll
        for (int r = 0; r < 16; ++r) tm[r] = fmaxf(sacc[0][r], sacc[1][r]);
#pragma unroll
        for (int s = 8; s > 0; s >>= 1)
#pragma unroll
            for (int r = 0; r < 8; ++r)
                if (r < s) tm[r] = fmaxf(tm[r], tm[r + s]);
        float mx = fmaxf(tm[0], __shfl_xor(tm[0], 32));
        const float m_new = fmaxf(m_run, mx);
        const float scale = fexp2(m_run - m_new);
        m_run = m_new;

#pragma unroll
        for (int kb = 0; kb < 2; ++kb)
#pragma unroll
            for (int r = 0; r < 16; ++r)
                sacc[kb][r] = fexp2(sacc[kb][r] - m_new);

        float ts[16];
#pragma unroll
        for (int r = 0; r < 16; ++r) ts[r] = sacc[0][r] + sacc[1][r];
#pragma unroll
        for (int s = 8; s > 0; s >>= 1)
#pragma unroll
            for (int r = 0; r < 8; ++r)
                if (r < s) ts[r] += ts[r + s];
        float sum = ts[0] + __shfl_xor(ts[0], 32);
        l_run = l_run * scale + sum;
#pragma unroll
        for (int db = 0; db < 2; ++db)
#pragma unroll
            for (int r = 0; r < 16; ++r) oacc[db][r] *= scale;

        // ---- pack P^T frags: keys kc*16 + hi*8 + j for own q ----
        // lane's reg r holds key kb*32 + (r&3) + 8*(r>>2) + 4*hi
        f16x8 pfrag[4];
#pragma unroll
        for (int kb = 0; kb < 2; ++kb)
#pragma unroll
            for (int lc = 0; lc < 2; ++lc) {
                const int rb = lc * 8;
                uint a = pkh(sacc[kb][rb + 0], sacc[kb][rb + 1]);
                uint b = pkh(sacc[kb][rb + 2], sacc[kb][rb + 3]);
                uint c = pkh(sacc[kb][rb + 4], sacc[kb][rb + 5]);
                uint d = pkh(sacc[kb][rb + 6], sacc[kb][rb + 7]);
                uint xa = __shfl_xor(a, 32), xb = __shfl_xor(b, 32);
                uint xc = __shfl_xor(c, 32), xd = __shfl_xor(d, 32);
                union { uint u[4]; f16x8 v; } f;
                f.u[0] = hi ? xc : a;
                f.u[1] = hi ? xd : b;
                f.u[2] = hi ? c : xa;
                f.u[3] = hi ? d : xb;
                pfrag[kb * 2 + lc] = f.v;
            }

        // ---- O^T += V^T . P^T ----
#pragma unroll
        for (int db = 0; db < 2; ++db) {
            const int row = db * 32 + q;
            const int swz = (row & 7) << 4;
#pragma unroll
            for (int kc = 0; kc < 4; ++kc) {
                f16x8 vf = *(const f16x8*)(
                    (const char*)Vt[cur] + row * 128 + ((kc * 32 + hi * 16) ^ swz));
                oacc[db] = __builtin_amdgcn_mfma_f32_32x32x16_f16(
                    vf, pfrag[kc], oacc[db], 0, 0, 0);
            }
        }

        if (pf) writeV(cur ^ 1, vr0, vr1);   // write after compute (latency hidden)
        __syncthreads();
        cur ^= 1;
    }

    // ---- epilogue: O /= l, write f16 AO [B][T][D]; d = db*32+8g+4hi+i ----
    const float inv = 1.f / l_run;
    const int b = bh >> 4, h = bh & 15;
    ushort* orow = AO + ((size_t)(b * SEQ) + q0 + q) * D_MODEL + h * HD;
#pragma unroll
    for (int db = 0; db < 2; ++db)
#pragma unroll
        for (int g = 0; g < 4; ++g) {
            const int d = db * 32 + g * 8 + hi * 4;
            alignas(8) ushort e4[4];
#pragma unroll
            for (int i = 0; i < 4; ++i) e4[i] = f2h(oacc[db][g * 4 + i] * inv);
            *(uint2*)(orow + d) = *(const uint2*)e4;
        }
}

// ---------------------------------------------------------------------------
extern "C" void kernel_launch(void* const* d_in, const int* in_sizes, int n_in,
                              void* d_out, int out_size, void* d_ws, size_t ws_size,
                              hipStream_t stream)
{
    const float* x      = (const float*)d_in[0];  // (2, 2048, 1024)
    const float* w_qkv  = (const float*)d_in[1];  // (1024, 3072)
    const float* w_proj = (const float*)d_in[2];  // (1024, 1024)
    float* out = (float*)d_out;                   // (2, 2048, 1024) fp32

    ushort* Xh  = (ushort*)d_ws;                        // 4M
    ushort* WqT = Xh  + (size_t)MTOT * D_MODEL;         // 3M  [3072][1024]
    ushort* WpT = WqT + (size_t)3 * D_MODEL * D_MODEL;  // 1M  [1024][1024]
    ushort* Qw  = WpT + (size_t)D_MODEL * D_MODEL;      // 4M  [B][H][T][64]
    ushort* Kw  = Qw  + (size_t)MTOT * D_MODEL;
    ushort* Vw  = Kw  + (size_t)MTOT * D_MODEL;
    ushort* AOh = Vw  + (size_t)MTOT * D_MODEL;         // 4M  [B][T][D]

    dim3 blk(256);

    cast8<<<dim3(MTOT * D_MODEL / (8 * 256)), blk, 0, stream>>>(x, Xh, MTOT * D_MODEL);
    transpose_cast<<<dim3(3 * D_MODEL / 32, D_MODEL / 32), blk, 0, stream>>>(
        w_qkv, WqT, D_MODEL, 3 * D_MODEL);
    transpose_cast<<<dim3(D_MODEL / 32, D_MODEL / 32), blk, 0, stream>>>(
        w_proj, WpT, D_MODEL, D_MODEL);

    gemm_mfma<0><<<dim3(3 * D_MODEL / 128, MTOT / 128), blk, 0, stream>>>(
        Xh, WqT, nullptr, Qw, Kw, Vw, 3 * D_MODEL);

    attn_mfma2<<<dim3(SEQ / 128, BSZ * NH), blk, 0, stream>>>(Qw, Kw, Vw, AOh);

    gemm_mfma<1><<<dim3(D_MODEL / 128, MTOT / 128), blk, 0, stream>>>(
        AOh, WpT, out, nullptr, nullptr, nullptr, D_MODEL);
}

// Round 6
// 151.493 us; speedup vs baseline: 7.6910x; 1.0463x over previous
//
#include <hip/hip_runtime.h>
#include <hip/hip_bf16.h>
#include <cmath>

#define D_MODEL 1024
#define NH 16
#define HD 64
#define BSZ 2
#define SEQ 2048
#define MTOT (BSZ * SEQ)   // 4096

typedef _Float16 f16x8 __attribute__((ext_vector_type(8)));
typedef __fp16   fp16x2 __attribute__((ext_vector_type(2)));  // cvt_pkrtz result type
typedef float    f32x4  __attribute__((ext_vector_type(4)));
typedef float    f32x16 __attribute__((ext_vector_type(16)));

// Q pre-scale: (1/sqrt(64)) * log2(e)  -> softmax runs in exp2 domain (1 instr)
#define QSCALE 0.18033688011112042f

__device__ __forceinline__ ushort f2h(float x) {
    union { _Float16 h; ushort u; } cv;
    cv.h = (_Float16)x;
    return cv.u;
}
__device__ __forceinline__ uint pkh(float a, float b) {   // pack 2 f32 -> 2 f16
    union { fp16x2 h; uint u; } cv;
    cv.h = __builtin_amdgcn_cvt_pkrtz(a, b);
    return cv.u;
}
__device__ __forceinline__ float fexp2(float x) {
    float r; asm("v_exp_f32 %0, %1" : "=v"(r) : "v"(x)); return r;
}
// async global->LDS, 16B/lane; lds base wave-uniform, data lands at base+lane*16
__device__ __forceinline__ void gload_lds16(const ushort* g, ushort* l) {
    __builtin_amdgcn_global_load_lds(
        (const __attribute__((address_space(1))) void*)g,
        (__attribute__((address_space(3))) void*)l, 16, 0, 0);
}

// ---------------------------------------------------------------------------
// fp32 -> f16 cast, 8 elems/thread
// ---------------------------------------------------------------------------
__global__ __launch_bounds__(256)
void cast8(const float* __restrict__ in, ushort* __restrict__ out, int n)
{
    const int i = (blockIdx.x * 256 + threadIdx.x) * 8;
    if (i >= n) return;
    float4 a = *(const float4*)(in + i);
    float4 b = *(const float4*)(in + i + 4);
    alignas(16) ushort h8[8];
    h8[0] = f2h(a.x); h8[1] = f2h(a.y); h8[2] = f2h(a.z); h8[3] = f2h(a.w);
    h8[4] = f2h(b.x); h8[5] = f2h(b.y); h8[6] = f2h(b.z); h8[7] = f2h(b.w);
    *(uint4*)(out + i) = *(const uint4*)h8;
}

// ---------------------------------------------------------------------------
// transpose + cast: in[R][C] fp32 -> out[C][R] f16.  32x32 LDS tile.
// ---------------------------------------------------------------------------
__global__ __launch_bounds__(256)
void transpose_cast(const float* __restrict__ in, ushort* __restrict__ out,
                    int R, int C)
{
    __shared__ float tile[32][33];
    const int t  = threadIdx.x;
    const int r0 = blockIdx.y * 32, c0 = blockIdx.x * 32;
    const int tr = t >> 5, tc = t & 31;   // 8 x 32
#pragma unroll
    for (int s = 0; s < 4; ++s)
        tile[tr + 8 * s][tc] = in[(size_t)(r0 + tr + 8 * s) * C + c0 + tc];
    __syncthreads();
#pragma unroll
    for (int s = 0; s < 4; ++s)
        out[(size_t)(c0 + tr + 8 * s) * R + r0 + tc] = f2h(tile[tc][tr + 8 * s]);
}

// ---------------------------------------------------------------------------
// MFMA GEMM (m97 structure): C[M][N] = A[M][1024] * Bt[N][1024]^T, f16 in,
// fp32 accum. 128x128 tile, 4 waves (2x2), BK=64, global_load_lds x16.
// MODE 0: QKV scatter -> f16 Q/K/V [B][H][T][64], Q scaled by QSCALE
// MODE 1: fp32 row-major out [M][N]
// ---------------------------------------------------------------------------
template <int MODE>
__global__ __launch_bounds__(256)
void gemm_mfma(const ushort* __restrict__ A, const ushort* __restrict__ Bt,
               float* __restrict__ outp,
               ushort* __restrict__ Qw, ushort* __restrict__ Kw,
               ushort* __restrict__ Vw, int N)
{
    __shared__ ushort As[128 * 64];
    __shared__ ushort Bs[128 * 64];

    const int t  = threadIdx.x;
    const int w  = t >> 6;
    const int l  = t & 63;
    const int lr = l & 15;
    const int lg = l >> 4;
    const int wr = w >> 1, wc = w & 1;
    const int m0 = blockIdx.y * 128, n0 = blockIdx.x * 128;

    const int srow = l >> 3;
    const int scol = (l & 7) * 8;

    const ushort* Ab = A  + (size_t)m0 * 1024;
    const ushort* Bb = Bt + (size_t)n0 * 1024;

    f32x4 acc[4][4];
#pragma unroll
    for (int i = 0; i < 4; ++i)
#pragma unroll
        for (int j = 0; j < 4; ++j) acc[i][j] = (f32x4){0.f, 0.f, 0.f, 0.f};

    for (int k0 = 0; k0 < 1024; k0 += 64) {
#pragma unroll
        for (int i = 0; i < 4; ++i) {
            const int r8 = (w * 4 + i) * 8;
            gload_lds16(Ab + (size_t)(r8 + srow) * 1024 + k0 + scol, &As[r8 * 64]);
            gload_lds16(Bb + (size_t)(r8 + srow) * 1024 + k0 + scol, &Bs[r8 * 64]);
        }
        __syncthreads();

#pragma unroll
        for (int kk = 0; kk < 2; ++kk) {
            f16x8 af[4], bf[4];
#pragma unroll
            for (int m = 0; m < 4; ++m)
                af[m] = *(const f16x8*)&As[(wr * 64 + m * 16 + lr) * 64 + kk * 32 + lg * 8];
#pragma unroll
            for (int n = 0; n < 4; ++n)
                bf[n] = *(const f16x8*)&Bs[(wc * 64 + n * 16 + lr) * 64 + kk * 32 + lg * 8];
#pragma unroll
            for (int m = 0; m < 4; ++m)
#pragma unroll
                for (int n = 0; n < 4; ++n)
                    acc[m][n] = __builtin_amdgcn_mfma_f32_16x16x32_f16(
                        af[m], bf[n], acc[m][n], 0, 0, 0);
        }
        __syncthreads();
    }

    if (MODE == 1) {
#pragma unroll
        for (int mf = 0; mf < 4; ++mf) {
            const int row = m0 + wr * 64 + mf * 16 + lg * 4;
#pragma unroll
            for (int nf = 0; nf < 4; ++nf) {
                const int col = n0 + wc * 64 + nf * 16 + lr;
#pragma unroll
                for (int i = 0; i < 4; ++i)
                    outp[(size_t)(row + i) * N + col] = acc[mf][nf][i];
            }
        }
    } else {
#pragma unroll
        for (int mf = 0; mf < 4; ++mf) {
            const int row = m0 + wr * 64 + mf * 16 + lg * 4;
            const int b   = row >> 11;
            const int tt0 = row & (SEQ - 1);
#pragma unroll
            for (int nf = 0; nf < 4; ++nf) {
                const int col   = n0 + wc * 64 + nf * 16 + lr;
                const int which = col >> 10;
                const int h     = (col >> 6) & 15;
                const int d     = col & 63;
                ushort* dst = (which == 0) ? Qw : (which == 1) ? Kw : Vw;
                const float sc = (which == 0) ? QSCALE : 1.0f;
#pragma unroll
                for (int i = 0; i < 4; ++i)
                    dst[((size_t)(b * NH + h) * SEQ + tt0 + i) * HD + d] =
                        f2h(acc[mf][nf][i] * sc);
            }
        }
    }
}

// ---------------------------------------------------------------------------
// Split-K swapped-operand MFMA flash attention.
// Block = 512 threads = 8 waves = 2 wave-groups x 4 waves.
//   group g handles keys [g*1024, g*1024+1024) for the SAME 128 q-rows.
//   per-group double-buffered K (row-major, swizzled via pre-swizzled
//   gload_lds source) and V^T (reg-staged transposed scatter, swizzled).
//   S^T = mfma(K, Q): C col = lane&31 = q -> softmax fully in-lane.
//   defer-max (T13, THR=8 in exp2 domain); setprio around MFMA (T5).
//   End: in-block combine via LDS (upper group parks m/l/O^T in retired
//   K/V space; lower group merges + stores). No extra HBM traffic.
// C/D layout (m74/m101): col=lane&31, row=(reg&3)+8*(reg>>2)+4*(lane>>5).
// ---------------------------------------------------------------------------
__global__ __launch_bounds__(512, 4)
void attn_mfma3(const ushort* __restrict__ Qw, const ushort* __restrict__ Kw,
                const ushort* __restrict__ Vw, ushort* __restrict__ AO)
{
    __shared__ ushort KsAll[2][2][64 * 64];   // [group][buf]  32 KB
    __shared__ ushort VtAll[2][2][64 * 64];   // 32 KB

    const int t    = threadIdx.x;
    const int w    = t >> 6;     // 0..7
    const int l    = t & 63;
    const int q    = l & 31;     // lane's q column
    const int hi   = l >> 5;     // 0/1
    const int half = w >> 2;     // KV half
    const int ww   = w & 3;      // wave-in-group

    const int bh = blockIdx.y;
    const int q0 = blockIdx.x * 128 + ww * 32;
    const int kbase = half * (SEQ / 2);
    const int NT = (SEQ / 2) / 64;   // 16 tiles per group

    const ushort* Qp = Qw + (size_t)bh * SEQ * HD;
    const ushort* Kp = Kw + (size_t)bh * SEQ * HD;
    const ushort* Vp = Vw + (size_t)bh * SEQ * HD;

    ushort (*Ks)[64 * 64] = KsAll[half];
    ushort (*Vt)[64 * 64] = VtAll[half];

    // Q B-frags: qf[kc] = Q[q0+q][kc*16 + hi*8 + (0..7)]
    f16x8 qf[4];
#pragma unroll
    for (int kc = 0; kc < 4; ++kc)
        qf[kc] = *(const f16x8*)(Qp + (size_t)(q0 + q) * HD + kc * 16 + hi * 8);

    f32x16 oacc[2];
#pragma unroll
    for (int db = 0; db < 2; ++db)
#pragma unroll
        for (int r = 0; r < 16; ++r) oacc[db][r] = 0.f;
    float m_run = -3.0e38f, l_run = 0.f;

    // K staging via gload_lds: linear dest, inverse-swizzled source
    auto stageK = [&](int buf, int k0) {
#pragma unroll
        for (int s = 0; s < 2; ++s) {
            const int c    = ww * 64 + l + 256 * s;     // 16B chunk id 0..511
            const int row  = c >> 3;
            const int unit = (c & 7) ^ (row & 7);
            gload_lds16(Kp + (size_t)(k0 + row) * HD + unit * 8,
                        &Ks[buf][(ww * 64 + 256 * s) * 8]);
        }
    };
    const int vkey = l;
    auto loadV = [&](int k0, uint4& r0, uint4& r1) {
        r0 = *(const uint4*)(Vp + (size_t)(k0 + vkey) * HD + ww * 8);
        r1 = *(const uint4*)(Vp + (size_t)(k0 + vkey) * HD + (ww + 4) * 8);
    };
    auto writeV = [&](int buf, uint4 r0, uint4 r1) {
        alignas(16) ushort e8[8];
        *(uint4*)e8 = r0;
#pragma unroll
        for (int i = 0; i < 8; ++i) {
            const int d = ww * 8 + i;
            *(ushort*)((char*)Vt[buf] + (d * 128 + ((vkey * 2) ^ (i << 4)))) = e8[i];
        }
        *(uint4*)e8 = r1;
#pragma unroll
        for (int i = 0; i < 8; ++i) {
            const int d = (ww + 4) * 8 + i;
            *(ushort*)((char*)Vt[buf] + (d * 128 + ((vkey * 2) ^ (i << 4)))) = e8[i];
        }
    };

    // prologue: stage tile 0 of this group's half
    {
        uint4 r0, r1;
        stageK(0, kbase);
        loadV(kbase, r0, r1);
        writeV(0, r0, r1);
    }
    __syncthreads();

    int cur = 0;
    for (int kt = 0; kt < NT; ++kt) {
        const bool pf = (kt + 1 < NT);
        uint4 vr0, vr1;
        if (pf) {                       // issue next-tile loads before compute
            stageK(cur ^ 1, kbase + (kt + 1) * 64);
            loadV(kbase + (kt + 1) * 64, vr0, vr1);
        }

        // ---- S^T = K . Q^T ----
        f32x16 sacc[2];
        __builtin_amdgcn_s_setprio(1);
#pragma unroll
        for (int kb = 0; kb < 2; ++kb) {
            f32x16 a;
#pragma unroll
            for (int r = 0; r < 16; ++r) a[r] = 0.f;
            const int row = kb * 32 + q;
            const int swz = (row & 7) << 4;
#pragma unroll
            for (int kc = 0; kc < 4; ++kc) {
                f16x8 kf = *(const f16x8*)(
                    (const char*)Ks[cur] + row * 128 + ((kc * 32 + hi * 16) ^ swz));
                a = __builtin_amdgcn_mfma_f32_32x32x16_f16(kf, qf[kc], a, 0, 0, 0);
            }
            sacc[kb] = a;
        }
        __builtin_amdgcn_s_setprio(0);

        // ---- in-lane online softmax (exp2 domain) with defer-max (T13) ----
        float tm[16];
#pragma unroll
        for (int r = 0; r < 16; ++r) tm[r] = fmaxf(sacc[0][r], sacc[1][r]);
#pragma unroll
        for (int s = 8; s > 0; s >>= 1)
#pragma unroll
            for (int r = 0; r < 8; ++r)
                if (r < s) tm[r] = fmaxf(tm[r], tm[r + s]);
        float mx = fmaxf(tm[0], __shfl_xor(tm[0], 32));

        if (__any(mx > m_run + 8.0f)) {    // rescale only when max grew enough
            const float m_new = fmaxf(m_run, mx);
            const float scale = fexp2(m_run - m_new);
            m_run = m_new;
            l_run *= scale;
#pragma unroll
            for (int db = 0; db < 2; ++db)
#pragma unroll
                for (int r = 0; r < 16; ++r) oacc[db][r] *= scale;
        }

#pragma unroll
        for (int kb = 0; kb < 2; ++kb)
#pragma unroll
            for (int r = 0; r < 16; ++r)
                sacc[kb][r] = fexp2(sacc[kb][r] - m_run);

        float ts[16];
#pragma unroll
        for (int r = 0; r < 16; ++r) ts[r] = sacc[0][r] + sacc[1][r];
#pragma unroll
        for (int s = 8; s > 0; s >>= 1)
#pragma unroll
            for (int r = 0; r < 8; ++r)
                if (r < s) ts[r] += ts[r + s];
        l_run += ts[0] + __shfl_xor(ts[0], 32);

        // ---- pack P^T frags (cvt_pkrtz + shfl_xor(32) + select) ----
        f16x8 pfrag[4];
#pragma unroll
        for (int kb = 0; kb < 2; ++kb)
#pragma unroll
            for (int lc = 0; lc < 2; ++lc) {
                const int rb = lc * 8;
                uint a = pkh(sacc[kb][rb + 0], sacc[kb][rb + 1]);
                uint b = pkh(sacc[kb][rb + 2], sacc[kb][rb + 3]);
                uint c = pkh(sacc[kb][rb + 4], sacc[kb][rb + 5]);
                uint d = pkh(sacc[kb][rb + 6], sacc[kb][rb + 7]);
                uint xa = __shfl_xor(a, 32), xb = __shfl_xor(b, 32);
                uint xc = __shfl_xor(c, 32), xd = __shfl_xor(d, 32);
                union { uint u[4]; f16x8 v; } f;
                f.u[0] = hi ? xc : a;
                f.u[1] = hi ? xd : b;
                f.u[2] = hi ? c : xa;
                f.u[3] = hi ? d : xb;
                pfrag[kb * 2 + lc] = f.v;
            }

        // ---- O^T += V^T . P^T ----
        __builtin_amdgcn_s_setprio(1);
#pragma unroll
        for (int db = 0; db < 2; ++db) {
            const int row = db * 32 + q;
            const int swz = (row & 7) << 4;
#pragma unroll
            for (int kc = 0; kc < 4; ++kc) {
                f16x8 vf = *(const f16x8*)(
                    (const char*)Vt[cur] + row * 128 + ((kc * 32 + hi * 16) ^ swz));
                oacc[db] = __builtin_amdgcn_mfma_f32_32x32x16_f16(
                    vf, pfrag[kc], oacc[db], 0, 0, 0);
            }
        }
        __builtin_amdgcn_s_setprio(0);

        if (pf) writeV(cur ^ 1, vr0, vr1);   // write after compute
        __syncthreads();
        cur ^= 1;
    }

    // ---- in-block split-K combine (reuse retired K/V LDS) ----
    float* oex = (float*)KsAll;            // [4][2][16][64] f32 = 32 KB exact
    float* mex = (float*)VtAll;            // [4][64]
    float* lex = mex + 256;                // [4][64]

    if (half == 1) {
        mex[ww * 64 + l] = m_run;
        lex[ww * 64 + l] = l_run;
#pragma unroll
        for (int db = 0; db < 2; ++db)
#pragma unroll
            for (int r = 0; r < 16; ++r)
                oex[(((ww * 2 + db) * 16) + r) * 64 + l] = oacc[db][r];
    }
    __syncthreads();
    if (half == 0) {
        const float m2 = mex[ww * 64 + l];
        const float l2 = lex[ww * 64 + l];
        const float mf = fmaxf(m_run, m2);
        float w1 = fexp2(m_run - mf), w2 = fexp2(m2 - mf);
        const float inv = 1.f / (l_run * w1 + l2 * w2);
        w1 *= inv; w2 *= inv;

        const int b = bh >> 4, h = bh & 15;
        ushort* orow = AO + ((size_t)(b * SEQ) + q0 + q) * D_MODEL + h * HD;
#pragma unroll
        for (int db = 0; db < 2; ++db)
#pragma unroll
            for (int g = 0; g < 4; ++g) {
                const int d = db * 32 + g * 8 + hi * 4;
                alignas(8) ushort e4[4];
#pragma unroll
                for (int i = 0; i < 4; ++i) {
                    const float o2 = oex[(((ww * 2 + db) * 16) + g * 4 + i) * 64 + l];
                    e4[i] = f2h(oacc[db][g * 4 + i] * w1 + o2 * w2);
                }
                *(uint2*)(orow + d) = *(const uint2*)e4;
            }
    }
}

// ---------------------------------------------------------------------------
extern "C" void kernel_launch(void* const* d_in, const int* in_sizes, int n_in,
                              void* d_out, int out_size, void* d_ws, size_t ws_size,
                              hipStream_t stream)
{
    const float* x      = (const float*)d_in[0];  // (2, 2048, 1024)
    const float* w_qkv  = (const float*)d_in[1];  // (1024, 3072)
    const float* w_proj = (const float*)d_in[2];  // (1024, 1024)
    float* out = (float*)d_out;                   // (2, 2048, 1024) fp32

    ushort* Xh  = (ushort*)d_ws;                        // 4M
    ushort* WqT = Xh  + (size_t)MTOT * D_MODEL;         // 3M  [3072][1024]
    ushort* WpT = WqT + (size_t)3 * D_MODEL * D_MODEL;  // 1M  [1024][1024]
    ushort* Qw  = WpT + (size_t)D_MODEL * D_MODEL;      // 4M  [B][H][T][64]
    ushort* Kw  = Qw  + (size_t)MTOT * D_MODEL;
    ushort* Vw  = Kw  + (size_t)MTOT * D_MODEL;
    ushort* AOh = Vw  + (size_t)MTOT * D_MODEL;         // 4M  [B][T][D]

    dim3 blk(256);

    cast8<<<dim3(MTOT * D_MODEL / (8 * 256)), blk, 0, stream>>>(x, Xh, MTOT * D_MODEL);
    transpose_cast<<<dim3(3 * D_MODEL / 32, D_MODEL / 32), blk, 0, stream>>>(
        w_qkv, WqT, D_MODEL, 3 * D_MODEL);
    transpose_cast<<<dim3(D_MODEL / 32, D_MODEL / 32), blk, 0, stream>>>(
        w_proj, WpT, D_MODEL, D_MODEL);

    gemm_mfma<0><<<dim3(3 * D_MODEL / 128, MTOT / 128), blk, 0, stream>>>(
        Xh, WqT, nullptr, Qw, Kw, Vw, 3 * D_MODEL);

    attn_mfma3<<<dim3(SEQ / 128, BSZ * NH), dim3(512), 0, stream>>>(Qw, Kw, Vw, AOh);

    gemm_mfma<1><<<dim3(D_MODEL / 128, MTOT / 128), blk, 0, stream>>>(
        AOh, WpT, out, nullptr, nullptr, nullptr, D_MODEL);
}

// Round 10
// 148.293 us; speedup vs baseline: 7.8570x; 1.0216x over previous
//
#include <hip/hip_runtime.h>
#include <hip/hip_bf16.h>
#include <cmath>

#define D_MODEL 1024
#define NH 16
#define HD 64
#define BSZ 2
#define SEQ 2048
#define MTOT (BSZ * SEQ)   // 4096

typedef _Float16 f16x8 __attribute__((ext_vector_type(8)));
typedef __fp16   fp16x2 __attribute__((ext_vector_type(2)));  // cvt_pkrtz result type
typedef float    f32x4  __attribute__((ext_vector_type(4)));
typedef float    f32x16 __attribute__((ext_vector_type(16)));
typedef unsigned int uivec2 __attribute__((ext_vector_type(2)));

// Q pre-scale: (1/sqrt(64)) * log2(e)  -> softmax runs in exp2 domain
#define QSCALE 0.18033688011112042f

__device__ __forceinline__ ushort f2h(float x) {
    union { _Float16 h; ushort u; } cv;
    cv.h = (_Float16)x;
    return cv.u;
}
__device__ __forceinline__ uint pkh(float a, float b) {   // pack 2 f32 -> 2 f16
    union { fp16x2 h; uint u; } cv;
    cv.h = __builtin_amdgcn_cvt_pkrtz(a, b);
    return cv.u;
}
__device__ __forceinline__ float fexp2(float x) {
    float r; asm("v_exp_f32 %0, %1" : "=v"(r) : "v"(x)); return r;
}
__device__ __forceinline__ float fmax3(float a, float b, float c) {
    return fmaxf(fmaxf(a, b), c);   // clang fuses to v_max3_f32
}
// async global->LDS, 16B/lane; lds base wave-uniform, data lands at base+lane*16
__device__ __forceinline__ void gload_lds16(const ushort* g, ushort* l) {
    __builtin_amdgcn_global_load_lds(
        (const __attribute__((address_space(1))) void*)g,
        (__attribute__((address_space(3))) void*)l, 16, 0, 0);
}

// ---------------------------------------------------------------------------
// fp32 -> f16 cast, 8 elems/thread
// ---------------------------------------------------------------------------
__global__ __launch_bounds__(256)
void cast8(const float* __restrict__ in, ushort* __restrict__ out, int n)
{
    const int i = (blockIdx.x * 256 + threadIdx.x) * 8;
    if (i >= n) return;
    float4 a = *(const float4*)(in + i);
    float4 b = *(const float4*)(in + i + 4);
    alignas(16) ushort h8[8];
    h8[0] = f2h(a.x); h8[1] = f2h(a.y); h8[2] = f2h(a.z); h8[3] = f2h(a.w);
    h8[4] = f2h(b.x); h8[5] = f2h(b.y); h8[6] = f2h(b.z); h8[7] = f2h(b.w);
    *(uint4*)(out + i) = *(const uint4*)h8;
}

// ---------------------------------------------------------------------------
// transpose + cast both weights in ONE launch: z<3 -> w_qkv slab z, z=3 -> w_proj
// in[1024][C] fp32 -> out[C][1024] f16, 32x32 LDS tiles
// ---------------------------------------------------------------------------
__global__ __launch_bounds__(256)
void transpose_cast2(const float* __restrict__ A, const float* __restrict__ B,
                     ushort* __restrict__ At, ushort* __restrict__ Bt)
{
    __shared__ float tile[32][33];
    const int z = blockIdx.z;
    const float* in = (z < 3) ? A : B;
    ushort* out     = (z < 3) ? At : Bt;
    const int C     = (z < 3) ? 3 * D_MODEL : D_MODEL;
    const int cb    = (z < 3) ? z * 32 + blockIdx.x : blockIdx.x;
    const int R = D_MODEL;
    const int t  = threadIdx.x;
    const int r0 = blockIdx.y * 32, c0 = cb * 32;
    const int tr = t >> 5, tc = t & 31;   // 8 x 32
#pragma unroll
    for (int s = 0; s < 4; ++s)
        tile[tr + 8 * s][tc] = in[(size_t)(r0 + tr + 8 * s) * C + c0 + tc];
    __syncthreads();
#pragma unroll
    for (int s = 0; s < 4; ++s)
        out[(size_t)(c0 + tr + 8 * s) * R + r0 + tc] = f2h(tile[tc][tr + 8 * s]);
}

// ---------------------------------------------------------------------------
// MFMA GEMM (m97 structure): C[M][N] = A[M][1024] * Bt[N][1024]^T, f16 in,
// fp32 accum. 128x128 tile, 4 waves (2x2), BK=64, global_load_lds x16.
// MODE 0: QKV scatter -> f16 Q/K/V [B][H][T][64], Q scaled by QSCALE
// MODE 1: fp32 row-major out [M][N]
// ---------------------------------------------------------------------------
template <int MODE>
__global__ __launch_bounds__(256)
void gemm_mfma(const ushort* __restrict__ A, const ushort* __restrict__ Bt,
               float* __restrict__ outp,
               ushort* __restrict__ Qw, ushort* __restrict__ Kw,
               ushort* __restrict__ Vw, int N)
{
    __shared__ ushort As[128 * 64];
    __shared__ ushort Bs[128 * 64];

    const int t  = threadIdx.x;
    const int w  = t >> 6;
    const int l  = t & 63;
    const int lr = l & 15;
    const int lg = l >> 4;
    const int wr = w >> 1, wc = w & 1;
    const int m0 = blockIdx.y * 128, n0 = blockIdx.x * 128;

    const int srow = l >> 3;
    const int scol = (l & 7) * 8;

    const ushort* Ab = A  + (size_t)m0 * 1024;
    const ushort* Bb = Bt + (size_t)n0 * 1024;

    f32x4 acc[4][4];
#pragma unroll
    for (int i = 0; i < 4; ++i)
#pragma unroll
        for (int j = 0; j < 4; ++j) acc[i][j] = (f32x4){0.f, 0.f, 0.f, 0.f};

    for (int k0 = 0; k0 < 1024; k0 += 64) {
#pragma unroll
        for (int i = 0; i < 4; ++i) {
            const int r8 = (w * 4 + i) * 8;
            gload_lds16(Ab + (size_t)(r8 + srow) * 1024 + k0 + scol, &As[r8 * 64]);
            gload_lds16(Bb + (size_t)(r8 + srow) * 1024 + k0 + scol, &Bs[r8 * 64]);
        }
        __syncthreads();

#pragma unroll
        for (int kk = 0; kk < 2; ++kk) {
            f16x8 af[4], bf[4];
#pragma unroll
            for (int m = 0; m < 4; ++m)
                af[m] = *(const f16x8*)&As[(wr * 64 + m * 16 + lr) * 64 + kk * 32 + lg * 8];
#pragma unroll
            for (int n = 0; n < 4; ++n)
                bf[n] = *(const f16x8*)&Bs[(wc * 64 + n * 16 + lr) * 64 + kk * 32 + lg * 8];
#pragma unroll
            for (int m = 0; m < 4; ++m)
#pragma unroll
                for (int n = 0; n < 4; ++n)
                    acc[m][n] = __builtin_amdgcn_mfma_f32_16x16x32_f16(
                        af[m], bf[n], acc[m][n], 0, 0, 0);
        }
        __syncthreads();
    }

    if (MODE == 1) {
#pragma unroll
        for (int mf = 0; mf < 4; ++mf) {
            const int row = m0 + wr * 64 + mf * 16 + lg * 4;
#pragma unroll
            for (int nf = 0; nf < 4; ++nf) {
                const int col = n0 + wc * 64 + nf * 16 + lr;
#pragma unroll
                for (int i = 0; i < 4; ++i)
                    outp[(size_t)(row + i) * N + col] = acc[mf][nf][i];
            }
        }
    } else {
#pragma unroll
        for (int mf = 0; mf < 4; ++mf) {
            const int row = m0 + wr * 64 + mf * 16 + lg * 4;
            const int b   = row >> 11;
            const int tt0 = row & (SEQ - 1);
#pragma unroll
            for (int nf = 0; nf < 4; ++nf) {
                const int col   = n0 + wc * 64 + nf * 16 + lr;
                const int which = col >> 10;
                const int h     = (col >> 6) & 15;
                const int d     = col & 63;
                ushort* dst = (which == 0) ? Qw : (which == 1) ? Kw : Vw;
                const float sc = (which == 0) ? QSCALE : 1.0f;
#pragma unroll
                for (int i = 0; i < 4; ++i)
                    dst[((size_t)(b * NH + h) * SEQ + tt0 + i) * HD + d] =
                        f2h(acc[mf][nf][i] * sc);
            }
        }
    }
}

// ---------------------------------------------------------------------------
// Split-K swapped-operand MFMA flash attention, v6.
// = round-6 PROVEN structure (reg-staged transposed V scatter, swizzled
//   ds_read_b128 for V-frags) + max3 tree (with partner shfl) + permlane32
//   pack (exonerated by the R8/R9 identical-result experiment).
// Block = 512 threads = 2 wave-groups x 4 waves; group g owns keys
// [g*1024,(g+1)*1024); in-block LDS split-K combine.
// C/D layout (m74/m101): col=lane&31, row=(reg&3)+8*(reg>>2)+4*(lane>>5).
// ---------------------------------------------------------------------------
__global__ __launch_bounds__(512, 4)
void attn_mfma6(const ushort* __restrict__ Qw, const ushort* __restrict__ Kw,
                const ushort* __restrict__ Vw, ushort* __restrict__ AO)
{
    __shared__ ushort KsAll[2][2][64 * 64];   // [group][buf] 32 KB
    __shared__ ushort VtAll[2][2][64 * 64];   // [group][buf] 32 KB, V^T swizzled

    const int t    = threadIdx.x;
    const int w    = t >> 6;     // 0..7
    const int l    = t & 63;
    const int q    = l & 31;     // lane's q column
    const int hi   = l >> 5;     // 0/1
    const int half = w >> 2;     // KV half
    const int ww   = w & 3;      // wave-in-group

    const int bh = blockIdx.y;
    const int q0 = blockIdx.x * 128 + ww * 32;
    const int kbase = half * (SEQ / 2);
    const int NT = (SEQ / 2) / 64;   // 16 tiles per group

    const ushort* Qp = Qw + (size_t)bh * SEQ * HD;
    const ushort* Kp = Kw + (size_t)bh * SEQ * HD;
    const ushort* Vp = Vw + (size_t)bh * SEQ * HD;

    ushort (*Ks)[64 * 64] = KsAll[half];
    ushort (*Vt)[64 * 64] = VtAll[half];

    // Q B-frags: qf[kc] = Q[q0+q][kc*16 + hi*8 + (0..7)]
    f16x8 qf[4];
#pragma unroll
    for (int kc = 0; kc < 4; ++kc)
        qf[kc] = *(const f16x8*)(Qp + (size_t)(q0 + q) * HD + kc * 16 + hi * 8);

    f32x16 oacc[2];
#pragma unroll
    for (int db = 0; db < 2; ++db)
#pragma unroll
        for (int r = 0; r < 16; ++r) oacc[db][r] = 0.f;
    float m_run = -3.0e38f, l_run = 0.f;

    // K staging: linear dest, inverse-swizzled source (proven r6)
    auto stageK = [&](int buf, int k0) {
#pragma unroll
        for (int s = 0; s < 2; ++s) {
            const int c    = ww * 64 + l + 256 * s;
            const int row  = c >> 3;
            const int unit = (c & 7) ^ (row & 7);
            gload_lds16(Kp + (size_t)(k0 + row) * HD + unit * 8,
                        &Ks[buf][(ww * 64 + 256 * s) * 8]);
        }
    };
    // V: reg-staged, transposed+swizzled scatter (proven r6; T14 split)
    const int vkey = l;
    auto loadV = [&](int k0, uint4& r0, uint4& r1) {
        r0 = *(const uint4*)(Vp + (size_t)(k0 + vkey) * HD + ww * 8);
        r1 = *(const uint4*)(Vp + (size_t)(k0 + vkey) * HD + (ww + 4) * 8);
    };
    auto writeV = [&](int buf, uint4 r0, uint4 r1) {
        alignas(16) ushort e8[8];
        *(uint4*)e8 = r0;
#pragma unroll
        for (int i = 0; i < 8; ++i) {
            const int d = ww * 8 + i;
            *(ushort*)((char*)Vt[buf] + (d * 128 + ((vkey * 2) ^ (i << 4)))) = e8[i];
        }
        *(uint4*)e8 = r1;
#pragma unroll
        for (int i = 0; i < 8; ++i) {
            const int d = (ww + 4) * 8 + i;
            *(ushort*)((char*)Vt[buf] + (d * 128 + ((vkey * 2) ^ (i << 4)))) = e8[i];
        }
    };

    // prologue
    {
        uint4 r0, r1;
        stageK(0, kbase);
        loadV(kbase, r0, r1);
        writeV(0, r0, r1);
    }
    __syncthreads();

    int cur = 0;
    for (int kt = 0; kt < NT; ++kt) {
        const bool pf = (kt + 1 < NT);
        uint4 vr0, vr1;
        if (pf) {                       // issue next-tile loads before compute
            stageK(cur ^ 1, kbase + (kt + 1) * 64);
            loadV(kbase + (kt + 1) * 64, vr0, vr1);
        }

        // ---- S^T = K . Q^T ----
        f32x16 sacc[2];
        __builtin_amdgcn_s_setprio(1);
#pragma unroll
        for (int kb = 0; kb < 2; ++kb) {
            f32x16 a;
#pragma unroll
            for (int r = 0; r < 16; ++r) a[r] = 0.f;
            const int row = kb * 32 + q;
            const int swz = (row & 7) << 4;
#pragma unroll
            for (int kc = 0; kc < 4; ++kc) {
                f16x8 kf = *(const f16x8*)(
                    (const char*)Ks[cur] + row * 128 + ((kc * 32 + hi * 16) ^ swz));
                a = __builtin_amdgcn_mfma_f32_32x32x16_f16(kf, qf[kc], a, 0, 0, 0);
            }
            sacc[kb] = a;
        }
        __builtin_amdgcn_s_setprio(0);

        // ---- in-lane online softmax (exp2), max3 tree + defer-max ----
        float p0 = fmax3(fmaxf(sacc[0][0], sacc[1][0]),
                         fmaxf(sacc[0][1], sacc[1][1]),
                         fmaxf(sacc[0][2], sacc[1][2]));
        float p1 = fmax3(fmaxf(sacc[0][3], sacc[1][3]),
                         fmaxf(sacc[0][4], sacc[1][4]),
                         fmaxf(sacc[0][5], sacc[1][5]));
        float p2 = fmax3(fmaxf(sacc[0][6], sacc[1][6]),
                         fmaxf(sacc[0][7], sacc[1][7]),
                         fmaxf(sacc[0][8], sacc[1][8]));
        float p3 = fmax3(fmaxf(sacc[0][9], sacc[1][9]),
                         fmaxf(sacc[0][10], sacc[1][10]),
                         fmaxf(sacc[0][11], sacc[1][11]));
        float p4 = fmax3(fmaxf(sacc[0][12], sacc[1][12]),
                         fmaxf(sacc[0][13], sacc[1][13]),
                         fmaxf(sacc[0][14], sacc[1][14]));
        float p5 = fmaxf(sacc[0][15], sacc[1][15]);
        float mx = fmaxf(fmax3(p0, p1, p2), fmax3(p3, p4, p5));
        mx = fmaxf(mx, __shfl_xor(mx, 32));   // combine partner half-row

        if (__any(mx > m_run + 8.0f)) {    // rescale only when max grew enough
            const float m_new = fmaxf(m_run, mx);
            const float scale = fexp2(m_run - m_new);
            m_run = m_new;
            l_run *= scale;
#pragma unroll
            for (int db = 0; db < 2; ++db)
#pragma unroll
                for (int r = 0; r < 16; ++r) oacc[db][r] *= scale;
        }

#pragma unroll
        for (int kb = 0; kb < 2; ++kb)
#pragma unroll
            for (int r = 0; r < 16; ++r)
                sacc[kb][r] = fexp2(sacc[kb][r] - m_run);

        float ts[16];
#pragma unroll
        for (int r = 0; r < 16; ++r) ts[r] = sacc[0][r] + sacc[1][r];
#pragma unroll
        for (int s = 8; s > 0; s >>= 1)
#pragma unroll
            for (int r = 0; r < 8; ++r)
                if (r < s) ts[r] += ts[r + s];
        l_run += ts[0] + __shfl_xor(ts[0], 32);

        // ---- pack P^T frags: cvt_pkrtz + permlane32_swap (exonerated) ----
        f16x8 pfrag[4];
#pragma unroll
        for (int kb = 0; kb < 2; ++kb)
#pragma unroll
            for (int lc = 0; lc < 2; ++lc) {
                const int rb = lc * 8;
                uint a = pkh(sacc[kb][rb + 0], sacc[kb][rb + 1]);
                uint b = pkh(sacc[kb][rb + 2], sacc[kb][rb + 3]);
                uint c = pkh(sacc[kb][rb + 4], sacc[kb][rb + 5]);
                uint d = pkh(sacc[kb][rb + 6], sacc[kb][rb + 7]);
                uivec2 r0 = __builtin_amdgcn_permlane32_swap(a, c, false, false);
                uivec2 r1 = __builtin_amdgcn_permlane32_swap(b, d, false, false);
                union { uint u[4]; f16x8 v; } f;
                f.u[0] = r0.x;
                f.u[1] = r1.x;
                f.u[2] = r0.y;
                f.u[3] = r1.y;
                pfrag[kb * 2 + lc] = f.v;
            }

        // ---- O^T += V^T . P^T  (proven swizzled ds_read_b128 path) ----
        __builtin_amdgcn_s_setprio(1);
#pragma unroll
        for (int db = 0; db < 2; ++db) {
            const int row = db * 32 + q;
            const int swz = (row & 7) << 4;
#pragma unroll
            for (int kc = 0; kc < 4; ++kc) {
                f16x8 vf = *(const f16x8*)(
                    (const char*)Vt[cur] + row * 128 + ((kc * 32 + hi * 16) ^ swz));
                oacc[db] = __builtin_amdgcn_mfma_f32_32x32x16_f16(
                    vf, pfrag[kc], oacc[db], 0, 0, 0);
            }
        }
        __builtin_amdgcn_s_setprio(0);

        if (pf) writeV(cur ^ 1, vr0, vr1);   // write after compute
        __syncthreads();
        cur ^= 1;
    }

    // ---- in-block split-K combine (reuse retired K/V LDS) ----
    float* oex = (float*)KsAll;            // [4][2][16][64] f32 = 32 KB
    float* mex = (float*)VtAll;            // [4][64]
    float* lex = mex + 256;                // [4][64]

    if (half == 1) {
        mex[ww * 64 + l] = m_run;
        lex[ww * 64 + l] = l_run;
#pragma unroll
        for (int db = 0; db < 2; ++db)
#pragma unroll
            for (int r = 0; r < 16; ++r)
                oex[(((ww * 2 + db) * 16) + r) * 64 + l] = oacc[db][r];
    }
    __syncthreads();
    if (half == 0) {
        const float m2 = mex[ww * 64 + l];
        const float l2 = lex[ww * 64 + l];
        const float mf = fmaxf(m_run, m2);
        float w1 = fexp2(m_run - mf), w2 = fexp2(m2 - mf);
        const float inv = 1.f / (l_run * w1 + l2 * w2);
        w1 *= inv; w2 *= inv;

        const int b = bh >> 4, h = bh & 15;
        ushort* orow = AO + ((size_t)(b * SEQ) + q0 + q) * D_MODEL + h * HD;
#pragma unroll
        for (int db = 0; db < 2; ++db)
#pragma unroll
            for (int g = 0; g < 4; ++g) {
                const int d = db * 32 + g * 8 + hi * 4;
                alignas(8) ushort e4[4];
#pragma unroll
                for (int i = 0; i < 4; ++i) {
                    const float o2 = oex[(((ww * 2 + db) * 16) + g * 4 + i) * 64 + l];
                    e4[i] = f2h(oacc[db][g * 4 + i] * w1 + o2 * w2);
                }
                *(uint2*)(orow + d) = *(const uint2*)e4;
            }
    }
}

// ---------------------------------------------------------------------------
extern "C" void kernel_launch(void* const* d_in, const int* in_sizes, int n_in,
                              void* d_out, int out_size, void* d_ws, size_t ws_size,
                              hipStream_t stream)
{
    const float* x      = (const float*)d_in[0];  // (2, 2048, 1024)
    const float* w_qkv  = (const float*)d_in[1];  // (1024, 3072)
    const float* w_proj = (const float*)d_in[2];  // (1024, 1024)
    float* out = (float*)d_out;                   // (2, 2048, 1024) fp32

    ushort* Xh  = (ushort*)d_ws;                        // 4M
    ushort* WqT = Xh  + (size_t)MTOT * D_MODEL;         // 3M  [3072][1024]
    ushort* WpT = WqT + (size_t)3 * D_MODEL * D_MODEL;  // 1M  [1024][1024]
    ushort* Qw  = WpT + (size_t)D_MODEL * D_MODEL;      // 4M  [B][H][T][64]
    ushort* Kw  = Qw  + (size_t)MTOT * D_MODEL;
    ushort* Vw  = Kw  + (size_t)MTOT * D_MODEL;
    ushort* AOh = Vw  + (size_t)MTOT * D_MODEL;         // 4M  [B][T][D]

    dim3 blk(256);

    cast8<<<dim3(MTOT * D_MODEL / (8 * 256)), blk, 0, stream>>>(x, Xh, MTOT * D_MODEL);
    transpose_cast2<<<dim3(32, 32, 4), blk, 0, stream>>>(w_qkv, w_proj, WqT, WpT);

    gemm_mfma<0><<<dim3(3 * D_MODEL / 128, MTOT / 128), blk, 0, stream>>>(
        Xh, WqT, nullptr, Qw, Kw, Vw, 3 * D_MODEL);

    attn_mfma6<<<dim3(SEQ / 128, BSZ * NH), dim3(512), 0, stream>>>(Qw, Kw, Vw, AOh);

    gemm_mfma<1><<<dim3(D_MODEL / 128, MTOT / 128), blk, 0, stream>>>(
        AOh, WpT, out, nullptr, nullptr, nullptr, D_MODEL);
}

// Round 11
// 142.461 us; speedup vs baseline: 8.1786x; 1.0409x over previous
//
#include <hip/hip_runtime.h>
#include <hip/hip_bf16.h>
#include <cmath>

#define D_MODEL 1024
#define NH 16
#define HD 64
#define BSZ 2
#define SEQ 2048
#define MTOT (BSZ * SEQ)   // 4096

typedef _Float16 f16x8 __attribute__((ext_vector_type(8)));
typedef __fp16   fp16x2 __attribute__((ext_vector_type(2)));  // cvt_pkrtz result type
typedef float    f32x4  __attribute__((ext_vector_type(4)));
typedef float    f32x16 __attribute__((ext_vector_type(16)));
typedef unsigned int uivec2 __attribute__((ext_vector_type(2)));

// Q pre-scale: (1/sqrt(64)) * log2(e)  -> softmax runs in exp2 domain
#define QSCALE 0.18033688011112042f

__device__ __forceinline__ ushort f2h(float x) {
    union { _Float16 h; ushort u; } cv;
    cv.h = (_Float16)x;
    return cv.u;
}
__device__ __forceinline__ uint pkh(float a, float b) {   // pack 2 f32 -> 2 f16
    union { fp16x2 h; uint u; } cv;
    cv.h = __builtin_amdgcn_cvt_pkrtz(a, b);
    return cv.u;
}
__device__ __forceinline__ float fexp2(float x) {
    float r; asm("v_exp_f32 %0, %1" : "=v"(r) : "v"(x)); return r;
}
__device__ __forceinline__ float fmax3(float a, float b, float c) {
    return fmaxf(fmaxf(a, b), c);   // clang fuses to v_max3_f32
}
// async global->LDS, 16B/lane; lds base wave-uniform, data lands at base+lane*16
__device__ __forceinline__ void gload_lds16(const ushort* g, ushort* l) {
    __builtin_amdgcn_global_load_lds(
        (const __attribute__((address_space(1))) void*)g,
        (__attribute__((address_space(3))) void*)l, 16, 0, 0);
}

// ---------------------------------------------------------------------------
// fp32 -> f16 cast, 8 elems/thread
// ---------------------------------------------------------------------------
__global__ __launch_bounds__(256)
void cast8(const float* __restrict__ in, ushort* __restrict__ out, int n)
{
    const int i = (blockIdx.x * 256 + threadIdx.x) * 8;
    if (i >= n) return;
    float4 a = *(const float4*)(in + i);
    float4 b = *(const float4*)(in + i + 4);
    alignas(16) ushort h8[8];
    h8[0] = f2h(a.x); h8[1] = f2h(a.y); h8[2] = f2h(a.z); h8[3] = f2h(a.w);
    h8[4] = f2h(b.x); h8[5] = f2h(b.y); h8[6] = f2h(b.z); h8[7] = f2h(b.w);
    *(uint4*)(out + i) = *(const uint4*)h8;
}

// ---------------------------------------------------------------------------
// transpose + cast both weights in ONE launch: z<3 -> w_qkv slab z, z=3 -> w_proj
// in[1024][C] fp32 -> out[C][1024] f16, 32x32 LDS tiles
// ---------------------------------------------------------------------------
__global__ __launch_bounds__(256)
void transpose_cast2(const float* __restrict__ A, const float* __restrict__ B,
                     ushort* __restrict__ At, ushort* __restrict__ Bt)
{
    __shared__ float tile[32][33];
    const int z = blockIdx.z;
    const float* in = (z < 3) ? A : B;
    ushort* out     = (z < 3) ? At : Bt;
    const int C     = (z < 3) ? 3 * D_MODEL : D_MODEL;
    const int cb    = (z < 3) ? z * 32 + blockIdx.x : blockIdx.x;
    const int R = D_MODEL;
    const int t  = threadIdx.x;
    const int r0 = blockIdx.y * 32, c0 = cb * 32;
    const int tr = t >> 5, tc = t & 31;   // 8 x 32
#pragma unroll
    for (int s = 0; s < 4; ++s)
        tile[tr + 8 * s][tc] = in[(size_t)(r0 + tr + 8 * s) * C + c0 + tc];
    __syncthreads();
#pragma unroll
    for (int s = 0; s < 4; ++s)
        out[(size_t)(c0 + tr + 8 * s) * R + r0 + tc] = f2h(tile[tc][tr + 8 * s]);
}

// ---------------------------------------------------------------------------
// MFMA GEMM (m97 structure): C[M][N] = A[M][1024] * Bt[N][1024]^T, f16 in,
// fp32 accum. 128x128 tile, 4 waves (2x2), BK=64, global_load_lds x16.
// MODE 0: QKV scatter -> f16 Q/K [B][H][T][64] (Q scaled by QSCALE),
//         V written TRANSPOSED -> Vt [B][H][64][T] (d-major, key-minor)
// MODE 1: fp32 row-major out [M][N]
// ---------------------------------------------------------------------------
template <int MODE>
__global__ __launch_bounds__(256)
void gemm_mfma(const ushort* __restrict__ A, const ushort* __restrict__ Bt,
               float* __restrict__ outp,
               ushort* __restrict__ Qw, ushort* __restrict__ Kw,
               ushort* __restrict__ Vw, int N)
{
    __shared__ ushort As[128 * 64];
    __shared__ ushort Bs[128 * 64];

    const int t  = threadIdx.x;
    const int w  = t >> 6;
    const int l  = t & 63;
    const int lr = l & 15;
    const int lg = l >> 4;
    const int wr = w >> 1, wc = w & 1;
    const int m0 = blockIdx.y * 128, n0 = blockIdx.x * 128;

    const int srow = l >> 3;
    const int scol = (l & 7) * 8;

    const ushort* Ab = A  + (size_t)m0 * 1024;
    const ushort* Bb = Bt + (size_t)n0 * 1024;

    f32x4 acc[4][4];
#pragma unroll
    for (int i = 0; i < 4; ++i)
#pragma unroll
        for (int j = 0; j < 4; ++j) acc[i][j] = (f32x4){0.f, 0.f, 0.f, 0.f};

    for (int k0 = 0; k0 < 1024; k0 += 64) {
#pragma unroll
        for (int i = 0; i < 4; ++i) {
            const int r8 = (w * 4 + i) * 8;
            gload_lds16(Ab + (size_t)(r8 + srow) * 1024 + k0 + scol, &As[r8 * 64]);
            gload_lds16(Bb + (size_t)(r8 + srow) * 1024 + k0 + scol, &Bs[r8 * 64]);
        }
        __syncthreads();

#pragma unroll
        for (int kk = 0; kk < 2; ++kk) {
            f16x8 af[4], bf[4];
#pragma unroll
            for (int m = 0; m < 4; ++m)
                af[m] = *(const f16x8*)&As[(wr * 64 + m * 16 + lr) * 64 + kk * 32 + lg * 8];
#pragma unroll
            for (int n = 0; n < 4; ++n)
                bf[n] = *(const f16x8*)&Bs[(wc * 64 + n * 16 + lr) * 64 + kk * 32 + lg * 8];
#pragma unroll
            for (int m = 0; m < 4; ++m)
#pragma unroll
                for (int n = 0; n < 4; ++n)
                    acc[m][n] = __builtin_amdgcn_mfma_f32_16x16x32_f16(
                        af[m], bf[n], acc[m][n], 0, 0, 0);
        }
        __syncthreads();
    }

    if (MODE == 1) {
#pragma unroll
        for (int mf = 0; mf < 4; ++mf) {
            const int row = m0 + wr * 64 + mf * 16 + lg * 4;
#pragma unroll
            for (int nf = 0; nf < 4; ++nf) {
                const int col = n0 + wc * 64 + nf * 16 + lr;
#pragma unroll
                for (int i = 0; i < 4; ++i)
                    outp[(size_t)(row + i) * N + col] = acc[mf][nf][i];
            }
        }
    } else {
#pragma unroll
        for (int mf = 0; mf < 4; ++mf) {
            const int row = m0 + wr * 64 + mf * 16 + lg * 4;
            const int b   = row >> 11;
            const int tt0 = row & (SEQ - 1);
#pragma unroll
            for (int nf = 0; nf < 4; ++nf) {
                const int col   = n0 + wc * 64 + nf * 16 + lr;
                const int which = col >> 10;
                const int h     = (col >> 6) & 15;
                const int d     = col & 63;
                if (which == 2) {
                    // V transposed: Vt[b][h][d][t], 4 consecutive t per reg group
                    ushort* p = Vw + (((size_t)(b * NH + h) * HD + d) * SEQ) + tt0;
                    alignas(8) ushort e4[4];
#pragma unroll
                    for (int i = 0; i < 4; ++i) e4[i] = f2h(acc[mf][nf][i]);
                    *(uint2*)p = *(const uint2*)e4;
                } else {
                    ushort* dst = (which == 0) ? Qw : Kw;
                    const float sc = (which == 0) ? QSCALE : 1.0f;
#pragma unroll
                    for (int i = 0; i < 4; ++i)
                        dst[((size_t)(b * NH + h) * SEQ + tt0 + i) * HD + d] =
                            f2h(acc[mf][nf][i] * sc);
                }
            }
        }
    }
}

// ---------------------------------------------------------------------------
// Split-K swapped-operand MFMA flash attention, v7.
// = v6 (round-10, passing) but V^T comes pre-transposed from global
//   (Vt [B][H][64][SEQ]) and is staged by gload_lds with the SAME
//   pre-swizzled-source pattern as K -> loadV/writeV machinery deleted.
//   LDS image of V^T is byte-identical to v6; PV reads unchanged.
// Block = 512 threads = 2 wave-groups x 4 waves; group g owns keys
// [g*1024,(g+1)*1024); in-block LDS split-K combine.
// C/D layout (m74/m101): col=lane&31, row=(reg&3)+8*(reg>>2)+4*(lane>>5).
// ---------------------------------------------------------------------------
__global__ __launch_bounds__(512, 4)
void attn_mfma7(const ushort* __restrict__ Qw, const ushort* __restrict__ Kw,
                const ushort* __restrict__ Vtg, ushort* __restrict__ AO)
{
    __shared__ ushort KsAll[2][2][64 * 64];   // [group][buf] 32 KB
    __shared__ ushort VtAll[2][2][64 * 64];   // [group][buf] 32 KB, V^T swizzled

    const int t    = threadIdx.x;
    const int w    = t >> 6;     // 0..7
    const int l    = t & 63;
    const int q    = l & 31;     // lane's q column
    const int hi   = l >> 5;     // 0/1
    const int half = w >> 2;     // KV half
    const int ww   = w & 3;      // wave-in-group

    const int bh = blockIdx.y;
    const int q0 = blockIdx.x * 128 + ww * 32;
    const int kbase = half * (SEQ / 2);
    const int NT = (SEQ / 2) / 64;   // 16 tiles per group

    const ushort* Qp = Qw  + (size_t)bh * SEQ * HD;
    const ushort* Kp = Kw  + (size_t)bh * SEQ * HD;
    const ushort* Vp = Vtg + (size_t)bh * HD * SEQ;   // [d][key] d-major

    ushort (*Ks)[64 * 64] = KsAll[half];
    ushort (*Vt)[64 * 64] = VtAll[half];

    // Q B-frags: qf[kc] = Q[q0+q][kc*16 + hi*8 + (0..7)]
    f16x8 qf[4];
#pragma unroll
    for (int kc = 0; kc < 4; ++kc)
        qf[kc] = *(const f16x8*)(Qp + (size_t)(q0 + q) * HD + kc * 16 + hi * 8);

    f32x16 oacc[2];
#pragma unroll
    for (int db = 0; db < 2; ++db)
#pragma unroll
        for (int r = 0; r < 16; ++r) oacc[db][r] = 0.f;
    float m_run = -3.0e38f, l_run = 0.f;

    // staging: linear dest, inverse-swizzled source (proven pattern).
    // chunk c: row = c>>3 (K: key, V: d), unit = (c&7)^(row&7) -> 8-elem offset
    auto stageK = [&](int buf, int k0) {
#pragma unroll
        for (int s = 0; s < 2; ++s) {
            const int c    = ww * 64 + l + 256 * s;
            const int row  = c >> 3;
            const int unit = (c & 7) ^ (row & 7);
            gload_lds16(Kp + (size_t)(k0 + row) * HD + unit * 8,
                        &Ks[buf][(ww * 64 + 256 * s) * 8]);
        }
    };
    auto stageV = [&](int buf, int k0) {
#pragma unroll
        for (int s = 0; s < 2; ++s) {
            const int c    = ww * 64 + l + 256 * s;
            const int row  = c >> 3;                 // d row
            const int unit = (c & 7) ^ (row & 7);
            gload_lds16(Vp + (size_t)row * SEQ + k0 + unit * 8,
                        &Vt[buf][(ww * 64 + 256 * s) * 8]);
        }
    };

    stageK(0, kbase);
    stageV(0, kbase);
    __syncthreads();

    int cur = 0;
    for (int kt = 0; kt < NT; ++kt) {
        if (kt + 1 < NT) {               // issue next-tile DMA before compute
            stageK(cur ^ 1, kbase + (kt + 1) * 64);
            stageV(cur ^ 1, kbase + (kt + 1) * 64);
        }

        // ---- S^T = K . Q^T ----
        f32x16 sacc[2];
        __builtin_amdgcn_s_setprio(1);
#pragma unroll
        for (int kb = 0; kb < 2; ++kb) {
            f32x16 a;
#pragma unroll
            for (int r = 0; r < 16; ++r) a[r] = 0.f;
            const int row = kb * 32 + q;
            const int swz = (row & 7) << 4;
#pragma unroll
            for (int kc = 0; kc < 4; ++kc) {
                f16x8 kf = *(const f16x8*)(
                    (const char*)Ks[cur] + row * 128 + ((kc * 32 + hi * 16) ^ swz));
                a = __builtin_amdgcn_mfma_f32_32x32x16_f16(kf, qf[kc], a, 0, 0, 0);
            }
            sacc[kb] = a;
        }
        __builtin_amdgcn_s_setprio(0);

        // ---- in-lane online softmax (exp2), max3 tree + defer-max ----
        float p0 = fmax3(fmaxf(sacc[0][0], sacc[1][0]),
                         fmaxf(sacc[0][1], sacc[1][1]),
                         fmaxf(sacc[0][2], sacc[1][2]));
        float p1 = fmax3(fmaxf(sacc[0][3], sacc[1][3]),
                         fmaxf(sacc[0][4], sacc[1][4]),
                         fmaxf(sacc[0][5], sacc[1][5]));
        float p2 = fmax3(fmaxf(sacc[0][6], sacc[1][6]),
                         fmaxf(sacc[0][7], sacc[1][7]),
                         fmaxf(sacc[0][8], sacc[1][8]));
        float p3 = fmax3(fmaxf(sacc[0][9], sacc[1][9]),
                         fmaxf(sacc[0][10], sacc[1][10]),
                         fmaxf(sacc[0][11], sacc[1][11]));
        float p4 = fmax3(fmaxf(sacc[0][12], sacc[1][12]),
                         fmaxf(sacc[0][13], sacc[1][13]),
                         fmaxf(sacc[0][14], sacc[1][14]));
        float p5 = fmaxf(sacc[0][15], sacc[1][15]);
        float mx = fmaxf(fmax3(p0, p1, p2), fmax3(p3, p4, p5));
        mx = fmaxf(mx, __shfl_xor(mx, 32));   // combine partner half-row

        if (__any(mx > m_run + 8.0f)) {    // rescale only when max grew enough
            const float m_new = fmaxf(m_run, mx);
            const float scale = fexp2(m_run - m_new);
            m_run = m_new;
            l_run *= scale;
#pragma unroll
            for (int db = 0; db < 2; ++db)
#pragma unroll
                for (int r = 0; r < 16; ++r) oacc[db][r] *= scale;
        }

#pragma unroll
        for (int kb = 0; kb < 2; ++kb)
#pragma unroll
            for (int r = 0; r < 16; ++r)
                sacc[kb][r] = fexp2(sacc[kb][r] - m_run);

        float ts[16];
#pragma unroll
        for (int r = 0; r < 16; ++r) ts[r] = sacc[0][r] + sacc[1][r];
#pragma unroll
        for (int s = 8; s > 0; s >>= 1)
#pragma unroll
            for (int r = 0; r < 8; ++r)
                if (r < s) ts[r] += ts[r + s];
        l_run += ts[0] + __shfl_xor(ts[0], 32);

        // ---- pack P^T frags: cvt_pkrtz + permlane32_swap ----
        f16x8 pfrag[4];
#pragma unroll
        for (int kb = 0; kb < 2; ++kb)
#pragma unroll
            for (int lc = 0; lc < 2; ++lc) {
                const int rb = lc * 8;
                uint a = pkh(sacc[kb][rb + 0], sacc[kb][rb + 1]);
                uint b = pkh(sacc[kb][rb + 2], sacc[kb][rb + 3]);
                uint c = pkh(sacc[kb][rb + 4], sacc[kb][rb + 5]);
                uint d = pkh(sacc[kb][rb + 6], sacc[kb][rb + 7]);
                uivec2 r0 = __builtin_amdgcn_permlane32_swap(a, c, false, false);
                uivec2 r1 = __builtin_amdgcn_permlane32_swap(b, d, false, false);
                union { uint u[4]; f16x8 v; } f;
                f.u[0] = r0.x;
                f.u[1] = r1.x;
                f.u[2] = r0.y;
                f.u[3] = r1.y;
                pfrag[kb * 2 + lc] = f.v;
            }

        // ---- O^T += V^T . P^T  (proven swizzled ds_read_b128 path) ----
        __builtin_amdgcn_s_setprio(1);
#pragma unroll
        for (int db = 0; db < 2; ++db) {
            const int row = db * 32 + q;
            const int swz = (row & 7) << 4;
#pragma unroll
            for (int kc = 0; kc < 4; ++kc) {
                f16x8 vf = *(const f16x8*)(
                    (const char*)Vt[cur] + row * 128 + ((kc * 32 + hi * 16) ^ swz));
                oacc[db] = __builtin_amdgcn_mfma_f32_32x32x16_f16(
                    vf, pfrag[kc], oacc[db], 0, 0, 0);
            }
        }
        __builtin_amdgcn_s_setprio(0);

        __syncthreads();
        cur ^= 1;
    }

    // ---- in-block split-K combine (reuse retired K/V LDS) ----
    float* oex = (float*)KsAll;            // [4][2][16][64] f32 = 32 KB
    float* mex = (float*)VtAll;            // [4][64]
    float* lex = mex + 256;                // [4][64]

    if (half == 1) {
        mex[ww * 64 + l] = m_run;
        lex[ww * 64 + l] = l_run;
#pragma unroll
        for (int db = 0; db < 2; ++db)
#pragma unroll
            for (int r = 0; r < 16; ++r)
                oex[(((ww * 2 + db) * 16) + r) * 64 + l] = oacc[db][r];
    }
    __syncthreads();
    if (half == 0) {
        const float m2 = mex[ww * 64 + l];
        const float l2 = lex[ww * 64 + l];
        const float mf = fmaxf(m_run, m2);
        float w1 = fexp2(m_run - mf), w2 = fexp2(m2 - mf);
        const float inv = 1.f / (l_run * w1 + l2 * w2);
        w1 *= inv; w2 *= inv;

        const int b = bh >> 4, h = bh & 15;
        ushort* orow = AO + ((size_t)(b * SEQ) + q0 + q) * D_MODEL + h * HD;
#pragma unroll
        for (int db = 0; db < 2; ++db)
#pragma unroll
            for (int g = 0; g < 4; ++g) {
                const int d = db * 32 + g * 8 + hi * 4;
                alignas(8) ushort e4[4];
#pragma unroll
                for (int i = 0; i < 4; ++i) {
                    const float o2 = oex[(((ww * 2 + db) * 16) + g * 4 + i) * 64 + l];
                    e4[i] = f2h(oacc[db][g * 4 + i] * w1 + o2 * w2);
                }
                *(uint2*)(orow + d) = *(const uint2*)e4;
            }
    }
}

// ---------------------------------------------------------------------------
extern "C" void kernel_launch(void* const* d_in, const int* in_sizes, int n_in,
                              void* d_out, int out_size, void* d_ws, size_t ws_size,
                              hipStream_t stream)
{
    const float* x      = (const float*)d_in[0];  // (2, 2048, 1024)
    const float* w_qkv  = (const float*)d_in[1];  // (1024, 3072)
    const float* w_proj = (const float*)d_in[2];  // (1024, 1024)
    float* out = (float*)d_out;                   // (2, 2048, 1024) fp32

    ushort* Xh  = (ushort*)d_ws;                        // 4M
    ushort* WqT = Xh  + (size_t)MTOT * D_MODEL;         // 3M  [3072][1024]
    ushort* WpT = WqT + (size_t)3 * D_MODEL * D_MODEL;  // 1M  [1024][1024]
    ushort* Qw  = WpT + (size_t)D_MODEL * D_MODEL;      // 4M  [B][H][T][64]
    ushort* Kw  = Qw  + (size_t)MTOT * D_MODEL;         // 4M  [B][H][T][64]
    ushort* Vt  = Kw  + (size_t)MTOT * D_MODEL;         // 4M  [B][H][64][T]
    ushort* AOh = Vt  + (size_t)MTOT * D_MODEL;         // 4M  [B][T][D]

    dim3 blk(256);

    cast8<<<dim3(MTOT * D_MODEL / (8 * 256)), blk, 0, stream>>>(x, Xh, MTOT * D_MODEL);
    transpose_cast2<<<dim3(32, 32, 4), blk, 0, stream>>>(w_qkv, w_proj, WqT, WpT);

    gemm_mfma<0><<<dim3(3 * D_MODEL / 128, MTOT / 128), blk, 0, stream>>>(
        Xh, WqT, nullptr, Qw, Kw, Vt, 3 * D_MODEL);

    attn_mfma7<<<dim3(SEQ / 128, BSZ * NH), dim3(512), 0, stream>>>(Qw, Kw, Vt, AOh);

    gemm_mfma<1><<<dim3(D_MODEL / 128, MTOT / 128), blk, 0, stream>>>(
        AOh, WpT, out, nullptr, nullptr, nullptr, D_MODEL);
}